// Round 7
// baseline (248.327 us; speedup 1.0000x reference)
//
#include <hip/hip_runtime.h>
#include <math.h>

// ---------------------------------------------------------------------------
// AGDN via CSR-gather, bf16 propagated features.
//   CSR build: part_hist -> scanA/B -> part_scatter -> bucket_build (fused
//   fine-hist+scan+rowptr+scatter in LDS, all writes coalesced).
//   GEMM: 8x8 register tile, x/W in LDS (KC=32), interleaved node mapping
//   (node = ng + 16*i) to keep LDS reads conflict-free.
//   Hops: wave-per-node, 8 lanes/edge uint4 bf16 gather, fp32 accum.
// ---------------------------------------------------------------------------

#define EPB 4096     // edges per partition block
#define CAP 8192     // LDS col capacity per bucket (avg ~4096)

__device__ __forceinline__ float bf2f(unsigned short u)
{
    unsigned int t = ((unsigned int)u) << 16;
    return __builtin_bit_cast(float, t);
}
__device__ __forceinline__ unsigned short f2bf(float f)
{
    unsigned int t = __builtin_bit_cast(unsigned int, f);
    t += 0x7FFFu + ((t >> 16) & 1u);          // round-to-nearest-even
    return (unsigned short)(t >> 16);
}
__device__ __forceinline__ void up2(unsigned int u, float& lo, float& hi)
{
    lo = __builtin_bit_cast(float, u << 16);
    hi = __builtin_bit_cast(float, u & 0xFFFF0000u);
}

// ---------------- layer-1 GEMM: 128 nodes x 128 outputs per block ----------
// cols 0..63 = x@W1^T -> h0 (bf16); cols 64..127 = x@resW1^T -> res (fp32)
#define PAD1 36
__global__ __launch_bounds__(256)
void gemm_l1_kernel(const float* __restrict__ x,
                    const float* __restrict__ W1, const float* __restrict__ Wres,
                    unsigned short* __restrict__ h0, float* __restrict__ res, int n)
{
    __shared__ float xs[128 * PAD1];
    __shared__ float ws[128 * PAD1];

    const int tid = threadIdx.x;
    const int node0 = blockIdx.x * 128;
    const int o_lane = tid & 15;     // outputs o = o_lane + 16j, j 0..7
    const int ng = tid >> 4;         // nodes ng + 16i, i 0..7

    float acc[8][8] = {};
    for (int kc = 0; kc < 128; kc += 32) {
        for (int i = tid; i < 128 * 8; i += 256) {
            int r = i >> 3, c4 = (i & 7) * 4;
            const float* wsrc = (r < 64) ? &W1[(size_t)r * 128 + kc + c4]
                                         : &Wres[(size_t)(r - 64) * 128 + kc + c4];
            *(float4*)&ws[r * PAD1 + c4] = *(const float4*)wsrc;
            int nn = node0 + r;
            float4 v = (nn < n) ? *(const float4*)&x[(size_t)nn * 128 + kc + c4]
                                : make_float4(0.f, 0.f, 0.f, 0.f);
            *(float4*)&xs[r * PAD1 + c4] = v;
        }
        __syncthreads();
        #pragma unroll 2
        for (int k4 = 0; k4 < 32; k4 += 4) {
            float4 xv[8];
            #pragma unroll
            for (int i = 0; i < 8; ++i)
                xv[i] = *(const float4*)&xs[(ng + 16 * i) * PAD1 + k4];
            #pragma unroll
            for (int j = 0; j < 8; ++j) {
                float4 wv = *(const float4*)&ws[(o_lane + 16 * j) * PAD1 + k4];
                #pragma unroll
                for (int i = 0; i < 8; ++i)
                    acc[i][j] += xv[i].x * wv.x + xv[i].y * wv.y
                               + xv[i].z * wv.z + xv[i].w * wv.w;
            }
        }
        __syncthreads();
    }

    #pragma unroll
    for (int i = 0; i < 8; ++i) {
        int nn = node0 + ng + 16 * i;
        if (nn < n) {
            #pragma unroll
            for (int j = 0; j < 8; ++j) {
                int o = o_lane + 16 * j;
                if (j < 4) h0[(size_t)nn * 64 + o] = f2bf(acc[i][j]);
                else       res[(size_t)nn * 64 + (o - 64)] = acc[i][j];
            }
        }
    }
}

// ---------------- layer-2 GEMM: 128 nodes x 64 outputs per block -----------
__global__ __launch_bounds__(256)
void gemm_l2_kernel(const float* __restrict__ h,
                    const float* __restrict__ W2,
                    unsigned short* __restrict__ h0, int n)
{
    __shared__ float xs[128 * PAD1];
    __shared__ float ws[64 * PAD1];

    const int tid = threadIdx.x;
    const int node0 = blockIdx.x * 128;
    const int o_lane = tid & 15;     // outputs o = o_lane + 16j, j 0..3
    const int ng = tid >> 4;         // nodes ng + 16i, i 0..7

    float acc[8][4] = {};
    for (int kc = 0; kc < 64; kc += 32) {
        for (int i = tid; i < 64 * 8; i += 256) {
            int r = i >> 3, c4 = (i & 7) * 4;
            *(float4*)&ws[r * PAD1 + c4] = *(const float4*)&W2[(size_t)r * 64 + kc + c4];
        }
        for (int i = tid; i < 128 * 8; i += 256) {
            int r = i >> 3, c4 = (i & 7) * 4;
            int nn = node0 + r;
            float4 v = (nn < n) ? *(const float4*)&h[(size_t)nn * 64 + kc + c4]
                                : make_float4(0.f, 0.f, 0.f, 0.f);
            *(float4*)&xs[r * PAD1 + c4] = v;
        }
        __syncthreads();
        #pragma unroll 2
        for (int k4 = 0; k4 < 32; k4 += 4) {
            float4 xv[8];
            #pragma unroll
            for (int i = 0; i < 8; ++i)
                xv[i] = *(const float4*)&xs[(ng + 16 * i) * PAD1 + k4];
            #pragma unroll
            for (int j = 0; j < 4; ++j) {
                float4 wv = *(const float4*)&ws[(o_lane + 16 * j) * PAD1 + k4];
                #pragma unroll
                for (int i = 0; i < 8; ++i)
                    acc[i][j] += xv[i].x * wv.x + xv[i].y * wv.y
                               + xv[i].z * wv.z + xv[i].w * wv.w;
            }
        }
        __syncthreads();
    }

    #pragma unroll
    for (int i = 0; i < 8; ++i) {
        int nn = node0 + ng + 16 * i;
        if (nn < n) {
            #pragma unroll
            for (int j = 0; j < 4; ++j)
                h0[(size_t)nn * 64 + o_lane + 16 * j] = f2bf(acc[i][j]);
        }
    }
}

// ---------------- CSR build ----------------
__global__ __launch_bounds__(256)
void part_hist_kernel(const int* __restrict__ dst, int* __restrict__ table,
                      int E, int NB)
{
    __shared__ int h[256];
    h[threadIdx.x] = 0;
    __syncthreads();
    int base = blockIdx.x * EPB;
    for (int i = threadIdx.x; i < EPB; i += 256) {
        int e = base + i;
        if (e < E) atomicAdd(&h[((unsigned)dst[e]) >> 8], 1);
    }
    __syncthreads();
    table[threadIdx.x * NB + blockIdx.x] = h[threadIdx.x];   // bin-major
}

__global__ __launch_bounds__(256)
void scanA_kernel(const int* __restrict__ cnt, int* __restrict__ excl,
                  int* __restrict__ bsum, int n)
{
    __shared__ int sh[256];
    int i = blockIdx.x * 256 + threadIdx.x;
    int v = (i < n) ? cnt[i] : 0;
    sh[threadIdx.x] = v;
    __syncthreads();
    #pragma unroll
    for (int off = 1; off < 256; off <<= 1) {
        int t = (threadIdx.x >= off) ? sh[threadIdx.x - off] : 0;
        __syncthreads();
        sh[threadIdx.x] += t;
        __syncthreads();
    }
    if (i < n) excl[i] = sh[threadIdx.x] - v;
    if (threadIdx.x == 255) bsum[blockIdx.x] = sh[255];
}

__global__ __launch_bounds__(256)
void scanB_kernel(const int* __restrict__ bsum, int* __restrict__ bofs, int nb)
{
    __shared__ int sh[256];
    int v = (threadIdx.x < nb) ? bsum[threadIdx.x] : 0;
    sh[threadIdx.x] = v;
    __syncthreads();
    #pragma unroll
    for (int off = 1; off < 256; off <<= 1) {
        int t = (threadIdx.x >= off) ? sh[threadIdx.x - off] : 0;
        __syncthreads();
        sh[threadIdx.x] += t;
        __syncthreads();
    }
    if (threadIdx.x < nb) bofs[threadIdx.x] = sh[threadIdx.x] - v;
}

__global__ __launch_bounds__(256)
void part_scatter_kernel(const int* __restrict__ src, const int* __restrict__ dst,
                         const int* __restrict__ exclT, const int* __restrict__ bofsT,
                         unsigned int* __restrict__ packed, int E, int NB)
{
    __shared__ int lhist[256];
    __shared__ int sh[256];
    __shared__ int lexcl[256];
    __shared__ int lcur[256];
    __shared__ int gb2[256];
    __shared__ unsigned int lp[EPB];
    __shared__ unsigned char lbin[EPB];

    const int tid = threadIdx.x;
    const int base = blockIdx.x * EPB;
    const int cntE = min(EPB, E - base);

    unsigned int pv[16];
    int pb[16];
    lhist[tid] = 0;
    __syncthreads();
    #pragma unroll
    for (int it = 0; it < 16; ++it) {
        int i = it * 256 + tid;
        pv[it] = 0; pb[it] = -1;
        if (i < cntE) {
            int e = base + i;
            unsigned int p = (((unsigned)dst[e]) << 16) | (unsigned)src[e];
            pv[it] = p;
            pb[it] = (int)(p >> 24);
            atomicAdd(&lhist[pb[it]], 1);
        }
    }
    __syncthreads();
    sh[tid] = lhist[tid];
    __syncthreads();
    #pragma unroll
    for (int off = 1; off < 256; off <<= 1) {
        int t = (tid >= off) ? sh[tid - off] : 0;
        __syncthreads();
        sh[tid] += t;
        __syncthreads();
    }
    lexcl[tid] = sh[tid] - lhist[tid];
    lcur[tid] = sh[tid] - lhist[tid];
    int ti = tid * NB + blockIdx.x;
    gb2[tid] = exclT[ti] + bofsT[ti >> 8] - lexcl[tid];
    __syncthreads();
    #pragma unroll
    for (int it = 0; it < 16; ++it) {
        if (pb[it] >= 0) {
            int slot = atomicAdd(&lcur[pb[it]], 1);
            lp[slot] = pv[it];
            lbin[slot] = (unsigned char)pb[it];
        }
    }
    __syncthreads();
    for (int i = tid; i < cntE; i += 256)
        packed[gb2[lbin[i]] + i] = lp[i];
}

// fused fine stage: hist + scan + rowptr + in-LDS scatter + coalesced col out
__global__ __launch_bounds__(256)
void bucket_build_kernel(const unsigned int* __restrict__ packed,
                         const int* __restrict__ exclT, const int* __restrict__ bofsT,
                         int* __restrict__ rowptr, int* __restrict__ col,
                         int E, int NB, int N)
{
    __shared__ int h[256];
    __shared__ int sh[256];
    __shared__ int lcur[256];
    __shared__ int colL[CAP];

    const int b = blockIdx.x;
    const int t = threadIdx.x;
    int i0 = exclT[b * NB] + bofsT[(b * NB) >> 8];
    int bn = (b + 1) * NB;
    int i1 = exclT[bn] + bofsT[bn >> 8];

    h[t] = 0;
    __syncthreads();
    for (int i = i0 + t; i < i1; i += 256)
        atomicAdd(&h[(packed[i] >> 16) & 255], 1);
    __syncthreads();
    sh[t] = h[t];
    __syncthreads();
    #pragma unroll
    for (int off = 1; off < 256; off <<= 1) {
        int v = (t >= off) ? sh[t - off] : 0;
        __syncthreads();
        sh[t] += v;
        __syncthreads();
    }
    int excl = sh[t] - h[t];
    int d = b * 256 + t;
    if (d < N) rowptr[d] = i0 + excl;            // coalesced rowptr write
    if (b == gridDim.x - 1 && t == 0) rowptr[N] = E;
    lcur[t] = excl;
    __syncthreads();
    for (int i = i0 + t; i < i1; i += 256) {
        unsigned int p = packed[i];
        int lo = (p >> 16) & 255;
        int s = (int)(p & 0xFFFFu);
        int r = atomicAdd(&lcur[lo], 1);
        if (r < CAP) colL[r] = s;
        else col[i0 + r] = s;
    }
    __syncthreads();
    int cB = i1 - i0;
    for (int i = t; i < cB && i < CAP; i += 256)
        col[i0 + i] = colL[i];
}

// ---------------- hop: wave per node; 8 lanes/edge, 8 edges/instr ----------
__global__ __launch_bounds__(256)
void hop_csr_kernel(const unsigned short* __restrict__ fin,
                    unsigned short* __restrict__ fout,
                    const int* __restrict__ rowptr, const int* __restrict__ col, int n)
{
    int node = blockIdx.x * 4 + (threadIdx.x >> 6);
    if (node >= n) return;
    int lane = threadIdx.x & 63;
    int sub = lane >> 3;            // edge slot 0..7
    int fo = (lane & 7) * 8;        // feature octet start

    int beg = rowptr[node], end = rowptr[node + 1];
    int deg = end - beg;
    float a[8] = {};
    for (int b = 0; b < deg; b += 16) {
        int e0 = beg + b + sub, e1 = e0 + 8;
        uint4 u0 = make_uint4(0, 0, 0, 0), u1 = make_uint4(0, 0, 0, 0);
        if (e0 < end) { int s = col[e0]; u0 = *(const uint4*)&fin[(size_t)s * 64 + fo]; }
        if (e1 < end) { int s = col[e1]; u1 = *(const uint4*)&fin[(size_t)s * 64 + fo]; }
        float lo, hi;
        up2(u0.x, lo, hi); a[0] += lo; a[1] += hi;
        up2(u0.y, lo, hi); a[2] += lo; a[3] += hi;
        up2(u0.z, lo, hi); a[4] += lo; a[5] += hi;
        up2(u0.w, lo, hi); a[6] += lo; a[7] += hi;
        up2(u1.x, lo, hi); a[0] += lo; a[1] += hi;
        up2(u1.y, lo, hi); a[2] += lo; a[3] += hi;
        up2(u1.z, lo, hi); a[4] += lo; a[5] += hi;
        up2(u1.w, lo, hi); a[6] += lo; a[7] += hi;
    }
    #pragma unroll
    for (int off = 8; off <= 32; off <<= 1)
        #pragma unroll
        for (int k = 0; k < 8; ++k)
            a[k] += __shfl_xor(a[k], off);
    if (sub == 0) {
        uint4 o;
        o.x = (unsigned)f2bf(a[0]) | ((unsigned)f2bf(a[1]) << 16);
        o.y = (unsigned)f2bf(a[2]) | ((unsigned)f2bf(a[3]) << 16);
        o.z = (unsigned)f2bf(a[4]) | ((unsigned)f2bf(a[5]) << 16);
        o.w = (unsigned)f2bf(a[6]) | ((unsigned)f2bf(a[7]) << 16);
        *(uint4*)&fout[(size_t)node * 64 + fo] = o;
    }
}

// ---------------- 3rd hop fused with attention combine ----------------
// MODE 0: layer 1 (res from fp32 res buffer, apply ELU); MODE 1: layer 2.
template<int MODE>
__global__ __launch_bounds__(256)
void hop3_combine_kernel(const unsigned short* __restrict__ h0,
                         const unsigned short* __restrict__ f1,
                         const unsigned short* __restrict__ f2,
                         const float* __restrict__ res, const float* __restrict__ att,
                         const float* __restrict__ bias, float* __restrict__ out,
                         const int* __restrict__ rowptr, const int* __restrict__ col, int n)
{
    int node = blockIdx.x * 4 + (threadIdx.x >> 6);
    if (node >= n) return;
    int lane = threadIdx.x & 63;
    int sub = lane >> 3;
    int fo = (lane & 7) * 8;
    size_t base = (size_t)node * 64 + lane;

    int beg = rowptr[node], end = rowptr[node + 1];
    int deg = end - beg;
    float a[8] = {};
    for (int b = 0; b < deg; b += 16) {
        int e0 = beg + b + sub, e1 = e0 + 8;
        uint4 u0 = make_uint4(0, 0, 0, 0), u1 = make_uint4(0, 0, 0, 0);
        if (e0 < end) { int s = col[e0]; u0 = *(const uint4*)&f2[(size_t)s * 64 + fo]; }
        if (e1 < end) { int s = col[e1]; u1 = *(const uint4*)&f2[(size_t)s * 64 + fo]; }
        float lo, hi;
        up2(u0.x, lo, hi); a[0] += lo; a[1] += hi;
        up2(u0.y, lo, hi); a[2] += lo; a[3] += hi;
        up2(u0.z, lo, hi); a[4] += lo; a[5] += hi;
        up2(u0.w, lo, hi); a[6] += lo; a[7] += hi;
        up2(u1.x, lo, hi); a[0] += lo; a[1] += hi;
        up2(u1.y, lo, hi); a[2] += lo; a[3] += hi;
        up2(u1.z, lo, hi); a[4] += lo; a[5] += hi;
        up2(u1.w, lo, hi); a[6] += lo; a[7] += hi;
    }
    #pragma unroll
    for (int off = 8; off <= 32; off <<= 1)
        #pragma unroll
        for (int k = 0; k < 8; ++k)
            a[k] += __shfl_xor(a[k], off);

    int q = lane >> 3;
    float c[8];
    #pragma unroll
    for (int k = 0; k < 8; ++k) c[k] = __shfl(a[k], q);
    int rs = lane & 7;
    float v3 = (rs == 0) ? c[0] : (rs == 1) ? c[1] : (rs == 2) ? c[2] :
               (rs == 3) ? c[3] : (rs == 4) ? c[4] : (rs == 5) ? c[5] :
               (rs == 6) ? c[6] : c[7];

    float v0 = bf2f(h0[base]), v1 = bf2f(f1[base]), v2 = bf2f(f2[base]);
    float alo = att[lane], ahi = att[64 + lane];

    float p0 = v0 * alo;
    float q0 = v0 * ahi;
    float q1 = v1 * ahi;
    float q2 = v2 * ahi;
    float q3 = v3 * ahi;
    #pragma unroll
    for (int off = 32; off > 0; off >>= 1) {
        p0 += __shfl_xor(p0, off);
        q0 += __shfl_xor(q0, off);
        q1 += __shfl_xor(q1, off);
        q2 += __shfl_xor(q2, off);
        q3 += __shfl_xor(q3, off);
    }
    float s0 = p0 + q0, s1 = p0 + q1, s2 = p0 + q2, s3 = p0 + q3;
    s0 = s0 > 0.f ? s0 : 0.2f * s0;
    s1 = s1 > 0.f ? s1 : 0.2f * s1;
    s2 = s2 > 0.f ? s2 : 0.2f * s2;
    s3 = s3 > 0.f ? s3 : 0.2f * s3;
    float m = fmaxf(fmaxf(s0, s1), fmaxf(s2, s3));
    float e0 = expf(s0 - m), e1 = expf(s1 - m), e2 = expf(s2 - m), e3 = expf(s3 - m);
    float inv = 1.f / (e0 + e1 + e2 + e3);
    float o = (e0 * v0 + e1 * v1 + e2 * v2 + e3 * v3) * inv;

    float r = (MODE == 0) ? res[base] : v0;
    o += r + bias[lane];
    if (MODE == 0) o = o > 0.f ? o : expm1f(o);
    out[base] = o;
}

extern "C" void kernel_launch(void* const* d_in, const int* in_sizes, int n_in,
                              void* d_out, int out_size, void* d_ws, size_t ws_size,
                              hipStream_t stream)
{
    const float* x     = (const float*)d_in[0];
    const int*   ei    = (const int*)  d_in[1];
    const float* W1    = (const float*)d_in[2];
    const float* att1  = (const float*)d_in[3];
    const float* bias1 = (const float*)d_in[4];
    const float* resW1 = (const float*)d_in[5];
    const float* W2    = (const float*)d_in[6];
    const float* att2  = (const float*)d_in[7];
    const float* bias2 = (const float*)d_in[8];

    const int N_ = in_sizes[0] / 128;
    const int E_ = in_sizes[1] / 2;
    const int* src = ei;
    const int* dst = ei + E_;

    float* out = (float*)d_out;
    size_t S = (size_t)N_ * 64;
    unsigned short* h0 = (unsigned short*)d_ws;          // S bf16
    unsigned short* f1 = h0 + S;                         // S bf16
    unsigned short* f2 = f1 + S;                         // S bf16
    int* rowptr = (int*)(f2 + S);                        // N+1
    int* col    = rowptr + (N_ + 1);                     // E

    const int NB    = (E_ + EPB - 1) / EPB;              // partition blocks (<=256)
    const int NBUCK = (N_ + 255) / 256;                  // dst buckets

    // aliases (consumed before f1 is first written by the hops)
    unsigned int* packed = (unsigned int*)f1;            // E uints
    int* table = (int*)(col + E_);                       // 256*NB
    int* exclT = table + 256 * NB;                       // 256*NB
    int* bsumT = exclT + 256 * NB;                       // 256
    int* bofsT = bsumT + 256;                            // 256

    dim3 blk(256);
    int grid_g   = (N_ + 127) / 128;
    int node_grid = (N_ + 3) / 4;
    int nT        = 256 * NB;
    int nbT       = (nT + 255) / 256;                    // == NB

    // ---------------- CSR build ----------------
    part_hist_kernel<<<NB, blk, 0, stream>>>(dst, table, E_, NB);
    scanA_kernel<<<nbT, blk, 0, stream>>>(table, exclT, bsumT, nT);
    scanB_kernel<<<1, blk, 0, stream>>>(bsumT, bofsT, nbT);
    part_scatter_kernel<<<NB, blk, 0, stream>>>(src, dst, exclT, bofsT, packed, E_, NB);
    bucket_build_kernel<<<NBUCK, blk, 0, stream>>>(packed, exclT, bofsT, rowptr, col,
                                                   E_, NB, N_);

    // ---------------- layer 1 ----------------
    gemm_l1_kernel<<<grid_g, blk, 0, stream>>>(x, W1, resW1, h0, out, N_);
    hop_csr_kernel<<<node_grid, blk, 0, stream>>>(h0, f1, rowptr, col, N_);
    hop_csr_kernel<<<node_grid, blk, 0, stream>>>(f1, f2, rowptr, col, N_);
    hop3_combine_kernel<0><<<node_grid, blk, 0, stream>>>(h0, f1, f2, out, att1, bias1, out,
                                                          rowptr, col, N_);

    // ---------------- layer 2 ----------------
    gemm_l2_kernel<<<grid_g, blk, 0, stream>>>(out, W2, h0, N_);
    hop_csr_kernel<<<node_grid, blk, 0, stream>>>(h0, f1, rowptr, col, N_);
    hop_csr_kernel<<<node_grid, blk, 0, stream>>>(f1, f2, rowptr, col, N_);
    hop3_combine_kernel<1><<<node_grid, blk, 0, stream>>>(h0, f1, f2, nullptr, att2, bias2, out,
                                                          rowptr, col, N_);
}

// Round 8
// 219.730 us; speedup vs baseline: 1.1301x; 1.1301x over previous
//
#include <hip/hip_runtime.h>
#include <math.h>

// ---------------------------------------------------------------------------
// AGDN via CSR-gather, bf16 propagated features.
//   GEMMs: bf16 MFMA (mfma_f32_16x16x32_bf16), fp32 accum. 64-node blocks,
//     wave = 16 nodes x all outputs. x/W staged in LDS as bf16 with row pad
//     136/72 elems (272/144B stride -> conflict-free b128 frag reads).
//   CSR build: part_hist -> scanA/B -> part_scatter -> bucket_build (LDS).
//   Hops: wave-per-node, 8 lanes/edge uint4 bf16 gather, fp32 accum.
// ---------------------------------------------------------------------------

#define EPB 4096     // edges per partition block
#define CAP 8192     // LDS col capacity per bucket (avg ~4096)

typedef __attribute__((ext_vector_type(8))) short bf16x8;
typedef __attribute__((ext_vector_type(4))) float f32x4;

__device__ __forceinline__ float bf2f(unsigned short u)
{
    unsigned int t = ((unsigned int)u) << 16;
    return __builtin_bit_cast(float, t);
}
__device__ __forceinline__ unsigned short f2bf(float f)
{
    unsigned int t = __builtin_bit_cast(unsigned int, f);
    t += 0x7FFFu + ((t >> 16) & 1u);          // round-to-nearest-even
    return (unsigned short)(t >> 16);
}
__device__ __forceinline__ void up2(unsigned int u, float& lo, float& hi)
{
    lo = __builtin_bit_cast(float, u << 16);
    hi = __builtin_bit_cast(float, u & 0xFFFF0000u);
}

// ---------------- weight pre-conversion (fp32 -> bf16, once) ---------------
__global__ __launch_bounds__(256)
void convert_w_kernel(const float* __restrict__ W1, const float* __restrict__ Wres,
                      const float* __restrict__ W2,
                      unsigned short* __restrict__ w1b, unsigned short* __restrict__ w2b)
{
    int i = blockIdx.x * 256 + threadIdx.x;
    if (i < 8192)       w1b[i] = f2bf(W1[i]);
    else if (i < 16384) w1b[i] = f2bf(Wres[i - 8192]);
    else if (i < 20480) w2b[i - 16384] = f2bf(W2[i - 16384]);
}

// ---------------- layer-1 GEMM (MFMA): 64 nodes/block, 128 outputs ---------
// w1b rows 0..63 = W1 (-> h0 bf16), rows 64..127 = resW1 (-> res fp32)
#define LD1 136   // bf16 elems per LDS row (272 B stride: 4-bank shift/row)
__global__ __launch_bounds__(256)
void gemm_l1_mfma(const float* __restrict__ x,
                  const unsigned short* __restrict__ w1b,
                  unsigned short* __restrict__ h0, float* __restrict__ res, int n)
{
    __shared__ unsigned short xs[64 * LD1];
    __shared__ unsigned short ws[128 * LD1];
    const int tid = threadIdx.x;
    const int n0 = blockIdx.x * 64;

    // stage W (bf16 global -> LDS, 16B chunks)
    for (int i = tid; i < 128 * 16; i += 256) {
        int r = i >> 4, c8 = (i & 15) * 8;
        *(uint4*)&ws[r * LD1 + c8] = *(const uint4*)&w1b[r * 128 + c8];
    }
    // stage x (fp32 global -> bf16 LDS)
    for (int i = tid; i < 64 * 32; i += 256) {
        int r = i >> 5, c4 = (i & 31) * 4;
        int nn = n0 + r;
        float4 v = (nn < n) ? *(const float4*)&x[(size_t)nn * 128 + c4]
                            : make_float4(0.f, 0.f, 0.f, 0.f);
        uint2 o;
        o.x = (unsigned)f2bf(v.x) | ((unsigned)f2bf(v.y) << 16);
        o.y = (unsigned)f2bf(v.z) | ((unsigned)f2bf(v.w) << 16);
        *(uint2*)&xs[r * LD1 + c4] = o;
    }
    __syncthreads();

    const int wv = tid >> 6, l = tid & 63;
    const int lrow = l & 15, lk = l >> 4;     // frag row / k-group
    f32x4 acc[8] = {};
    const unsigned short* ax = &xs[(wv * 16 + lrow) * LD1 + lk * 8];
    const unsigned short* bw = &ws[lrow * LD1 + lk * 8];

    #pragma unroll
    for (int s = 0; s < 4; ++s) {            // K = 128 = 4 x 32
        bf16x8 a = *(const bf16x8*)&ax[s * 32];
        #pragma unroll
        for (int t = 0; t < 8; ++t) {        // 8 output tiles of 16
            bf16x8 b = *(const bf16x8*)&bw[(size_t)t * 16 * LD1 + s * 32];
            acc[t] = __builtin_amdgcn_mfma_f32_16x16x32_bf16(a, b, acc[t], 0, 0, 0);
        }
    }

    #pragma unroll
    for (int t = 0; t < 8; ++t) {
        #pragma unroll
        for (int r = 0; r < 4; ++r) {        // D row = lk*4 + r, col = lrow
            int node = n0 + wv * 16 + lk * 4 + r;
            if (node < n) {
                if (t < 4) h0[(size_t)node * 64 + t * 16 + lrow] = f2bf(acc[t][r]);
                else       res[(size_t)node * 64 + (t - 4) * 16 + lrow] = acc[t][r];
            }
        }
    }
}

// ---------------- layer-2 GEMM (MFMA): 64 nodes/block, 64 outputs ----------
#define LD2 72    // 144 B stride
__global__ __launch_bounds__(256)
void gemm_l2_mfma(const float* __restrict__ h,
                  const unsigned short* __restrict__ w2b,
                  unsigned short* __restrict__ h0, int n)
{
    __shared__ unsigned short xs[64 * LD2];
    __shared__ unsigned short ws[64 * LD2];
    const int tid = threadIdx.x;
    const int n0 = blockIdx.x * 64;

    for (int i = tid; i < 64 * 8; i += 256) {
        int r = i >> 3, c8 = (i & 7) * 8;
        *(uint4*)&ws[r * LD2 + c8] = *(const uint4*)&w2b[r * 64 + c8];
    }
    for (int i = tid; i < 64 * 16; i += 256) {
        int r = i >> 4, c4 = (i & 15) * 4;
        int nn = n0 + r;
        float4 v = (nn < n) ? *(const float4*)&h[(size_t)nn * 64 + c4]
                            : make_float4(0.f, 0.f, 0.f, 0.f);
        uint2 o;
        o.x = (unsigned)f2bf(v.x) | ((unsigned)f2bf(v.y) << 16);
        o.y = (unsigned)f2bf(v.z) | ((unsigned)f2bf(v.w) << 16);
        *(uint2*)&xs[r * LD2 + c4] = o;
    }
    __syncthreads();

    const int wv = tid >> 6, l = tid & 63;
    const int lrow = l & 15, lk = l >> 4;
    f32x4 acc[4] = {};
    const unsigned short* ax = &xs[(wv * 16 + lrow) * LD2 + lk * 8];
    const unsigned short* bw = &ws[lrow * LD2 + lk * 8];

    #pragma unroll
    for (int s = 0; s < 2; ++s) {            // K = 64 = 2 x 32
        bf16x8 a = *(const bf16x8*)&ax[s * 32];
        #pragma unroll
        for (int t = 0; t < 4; ++t) {
            bf16x8 b = *(const bf16x8*)&bw[(size_t)t * 16 * LD2 + s * 32];
            acc[t] = __builtin_amdgcn_mfma_f32_16x16x32_bf16(a, b, acc[t], 0, 0, 0);
        }
    }

    #pragma unroll
    for (int t = 0; t < 4; ++t) {
        #pragma unroll
        for (int r = 0; r < 4; ++r) {
            int node = n0 + wv * 16 + lk * 4 + r;
            if (node < n)
                h0[(size_t)node * 64 + t * 16 + lrow] = f2bf(acc[t][r]);
        }
    }
}

// ---------------- CSR build ----------------
__global__ __launch_bounds__(256)
void part_hist_kernel(const int* __restrict__ dst, int* __restrict__ table,
                      int E, int NB)
{
    __shared__ int h[256];
    h[threadIdx.x] = 0;
    __syncthreads();
    int base = blockIdx.x * EPB;
    for (int i = threadIdx.x; i < EPB; i += 256) {
        int e = base + i;
        if (e < E) atomicAdd(&h[((unsigned)dst[e]) >> 8], 1);
    }
    __syncthreads();
    table[threadIdx.x * NB + blockIdx.x] = h[threadIdx.x];   // bin-major
}

__global__ __launch_bounds__(256)
void scanA_kernel(const int* __restrict__ cnt, int* __restrict__ excl,
                  int* __restrict__ bsum, int n)
{
    __shared__ int sh[256];
    int i = blockIdx.x * 256 + threadIdx.x;
    int v = (i < n) ? cnt[i] : 0;
    sh[threadIdx.x] = v;
    __syncthreads();
    #pragma unroll
    for (int off = 1; off < 256; off <<= 1) {
        int t = (threadIdx.x >= off) ? sh[threadIdx.x - off] : 0;
        __syncthreads();
        sh[threadIdx.x] += t;
        __syncthreads();
    }
    if (i < n) excl[i] = sh[threadIdx.x] - v;
    if (threadIdx.x == 255) bsum[blockIdx.x] = sh[255];
}

__global__ __launch_bounds__(256)
void scanB_kernel(const int* __restrict__ bsum, int* __restrict__ bofs, int nb)
{
    __shared__ int sh[256];
    int v = (threadIdx.x < nb) ? bsum[threadIdx.x] : 0;
    sh[threadIdx.x] = v;
    __syncthreads();
    #pragma unroll
    for (int off = 1; off < 256; off <<= 1) {
        int t = (threadIdx.x >= off) ? sh[threadIdx.x - off] : 0;
        __syncthreads();
        sh[threadIdx.x] += t;
        __syncthreads();
    }
    if (threadIdx.x < nb) bofs[threadIdx.x] = sh[threadIdx.x] - v;
}

__global__ __launch_bounds__(256)
void part_scatter_kernel(const int* __restrict__ src, const int* __restrict__ dst,
                         const int* __restrict__ exclT, const int* __restrict__ bofsT,
                         unsigned int* __restrict__ packed, int E, int NB)
{
    __shared__ int lhist[256];
    __shared__ int sh[256];
    __shared__ int lexcl[256];
    __shared__ int lcur[256];
    __shared__ int gb2[256];
    __shared__ unsigned int lp[EPB];
    __shared__ unsigned char lbin[EPB];

    const int tid = threadIdx.x;
    const int base = blockIdx.x * EPB;
    const int cntE = min(EPB, E - base);

    unsigned int pv[16];
    int pb[16];
    lhist[tid] = 0;
    __syncthreads();
    #pragma unroll
    for (int it = 0; it < 16; ++it) {
        int i = it * 256 + tid;
        pv[it] = 0; pb[it] = -1;
        if (i < cntE) {
            int e = base + i;
            unsigned int p = (((unsigned)dst[e]) << 16) | (unsigned)src[e];
            pv[it] = p;
            pb[it] = (int)(p >> 24);
            atomicAdd(&lhist[pb[it]], 1);
        }
    }
    __syncthreads();
    sh[tid] = lhist[tid];
    __syncthreads();
    #pragma unroll
    for (int off = 1; off < 256; off <<= 1) {
        int t = (tid >= off) ? sh[tid - off] : 0;
        __syncthreads();
        sh[tid] += t;
        __syncthreads();
    }
    lexcl[tid] = sh[tid] - lhist[tid];
    lcur[tid] = sh[tid] - lhist[tid];
    int ti = tid * NB + blockIdx.x;
    gb2[tid] = exclT[ti] + bofsT[ti >> 8] - lexcl[tid];
    __syncthreads();
    #pragma unroll
    for (int it = 0; it < 16; ++it) {
        if (pb[it] >= 0) {
            int slot = atomicAdd(&lcur[pb[it]], 1);
            lp[slot] = pv[it];
            lbin[slot] = (unsigned char)pb[it];
        }
    }
    __syncthreads();
    for (int i = tid; i < cntE; i += 256)
        packed[gb2[lbin[i]] + i] = lp[i];
}

// fused fine stage: hist + scan + rowptr + in-LDS scatter + coalesced col out
__global__ __launch_bounds__(256)
void bucket_build_kernel(const unsigned int* __restrict__ packed,
                         const int* __restrict__ exclT, const int* __restrict__ bofsT,
                         int* __restrict__ rowptr, int* __restrict__ col,
                         int E, int NB, int N)
{
    __shared__ int h[256];
    __shared__ int sh[256];
    __shared__ int lcur[256];
    __shared__ int colL[CAP];

    const int b = blockIdx.x;
    const int t = threadIdx.x;
    int i0 = exclT[b * NB] + bofsT[(b * NB) >> 8];
    int bn = (b + 1) * NB;
    int i1 = exclT[bn] + bofsT[bn >> 8];

    h[t] = 0;
    __syncthreads();
    for (int i = i0 + t; i < i1; i += 256)
        atomicAdd(&h[(packed[i] >> 16) & 255], 1);
    __syncthreads();
    sh[t] = h[t];
    __syncthreads();
    #pragma unroll
    for (int off = 1; off < 256; off <<= 1) {
        int v = (t >= off) ? sh[t - off] : 0;
        __syncthreads();
        sh[t] += v;
        __syncthreads();
    }
    int excl = sh[t] - h[t];
    int d = b * 256 + t;
    if (d < N) rowptr[d] = i0 + excl;            // coalesced rowptr write
    if (b == gridDim.x - 1 && t == 0) rowptr[N] = E;
    lcur[t] = excl;
    __syncthreads();
    for (int i = i0 + t; i < i1; i += 256) {
        unsigned int p = packed[i];
        int lo = (p >> 16) & 255;
        int s = (int)(p & 0xFFFFu);
        int r = atomicAdd(&lcur[lo], 1);
        if (r < CAP) colL[r] = s;
        else col[i0 + r] = s;
    }
    __syncthreads();
    int cB = i1 - i0;
    for (int i = t; i < cB && i < CAP; i += 256)
        col[i0 + i] = colL[i];
}

// ---------------- hop: wave per node; 8 lanes/edge, 8 edges/instr ----------
__global__ __launch_bounds__(256)
void hop_csr_kernel(const unsigned short* __restrict__ fin,
                    unsigned short* __restrict__ fout,
                    const int* __restrict__ rowptr, const int* __restrict__ col, int n)
{
    int node = blockIdx.x * 4 + (threadIdx.x >> 6);
    if (node >= n) return;
    int lane = threadIdx.x & 63;
    int sub = lane >> 3;            // edge slot 0..7
    int fo = (lane & 7) * 8;        // feature octet start

    int beg = rowptr[node], end = rowptr[node + 1];
    int deg = end - beg;
    float a[8] = {};
    for (int b = 0; b < deg; b += 16) {
        int e0 = beg + b + sub, e1 = e0 + 8;
        uint4 u0 = make_uint4(0, 0, 0, 0), u1 = make_uint4(0, 0, 0, 0);
        if (e0 < end) { int s = col[e0]; u0 = *(const uint4*)&fin[(size_t)s * 64 + fo]; }
        if (e1 < end) { int s = col[e1]; u1 = *(const uint4*)&fin[(size_t)s * 64 + fo]; }
        float lo, hi;
        up2(u0.x, lo, hi); a[0] += lo; a[1] += hi;
        up2(u0.y, lo, hi); a[2] += lo; a[3] += hi;
        up2(u0.z, lo, hi); a[4] += lo; a[5] += hi;
        up2(u0.w, lo, hi); a[6] += lo; a[7] += hi;
        up2(u1.x, lo, hi); a[0] += lo; a[1] += hi;
        up2(u1.y, lo, hi); a[2] += lo; a[3] += hi;
        up2(u1.z, lo, hi); a[4] += lo; a[5] += hi;
        up2(u1.w, lo, hi); a[6] += lo; a[7] += hi;
    }
    #pragma unroll
    for (int off = 8; off <= 32; off <<= 1)
        #pragma unroll
        for (int k = 0; k < 8; ++k)
            a[k] += __shfl_xor(a[k], off);
    if (sub == 0) {
        uint4 o;
        o.x = (unsigned)f2bf(a[0]) | ((unsigned)f2bf(a[1]) << 16);
        o.y = (unsigned)f2bf(a[2]) | ((unsigned)f2bf(a[3]) << 16);
        o.z = (unsigned)f2bf(a[4]) | ((unsigned)f2bf(a[5]) << 16);
        o.w = (unsigned)f2bf(a[6]) | ((unsigned)f2bf(a[7]) << 16);
        *(uint4*)&fout[(size_t)node * 64 + fo] = o;
    }
}

// ---------------- 3rd hop fused with attention combine ----------------
// MODE 0: layer 1 (res from fp32 res buffer, apply ELU); MODE 1: layer 2.
template<int MODE>
__global__ __launch_bounds__(256)
void hop3_combine_kernel(const unsigned short* __restrict__ h0,
                         const unsigned short* __restrict__ f1,
                         const unsigned short* __restrict__ f2,
                         const float* __restrict__ res, const float* __restrict__ att,
                         const float* __restrict__ bias, float* __restrict__ out,
                         const int* __restrict__ rowptr, const int* __restrict__ col, int n)
{
    int node = blockIdx.x * 4 + (threadIdx.x >> 6);
    if (node >= n) return;
    int lane = threadIdx.x & 63;
    int sub = lane >> 3;
    int fo = (lane & 7) * 8;
    size_t base = (size_t)node * 64 + lane;

    int beg = rowptr[node], end = rowptr[node + 1];
    int deg = end - beg;
    float a[8] = {};
    for (int b = 0; b < deg; b += 16) {
        int e0 = beg + b + sub, e1 = e0 + 8;
        uint4 u0 = make_uint4(0, 0, 0, 0), u1 = make_uint4(0, 0, 0, 0);
        if (e0 < end) { int s = col[e0]; u0 = *(const uint4*)&f2[(size_t)s * 64 + fo]; }
        if (e1 < end) { int s = col[e1]; u1 = *(const uint4*)&f2[(size_t)s * 64 + fo]; }
        float lo, hi;
        up2(u0.x, lo, hi); a[0] += lo; a[1] += hi;
        up2(u0.y, lo, hi); a[2] += lo; a[3] += hi;
        up2(u0.z, lo, hi); a[4] += lo; a[5] += hi;
        up2(u0.w, lo, hi); a[6] += lo; a[7] += hi;
        up2(u1.x, lo, hi); a[0] += lo; a[1] += hi;
        up2(u1.y, lo, hi); a[2] += lo; a[3] += hi;
        up2(u1.z, lo, hi); a[4] += lo; a[5] += hi;
        up2(u1.w, lo, hi); a[6] += lo; a[7] += hi;
    }
    #pragma unroll
    for (int off = 8; off <= 32; off <<= 1)
        #pragma unroll
        for (int k = 0; k < 8; ++k)
            a[k] += __shfl_xor(a[k], off);

    int q = lane >> 3;
    float c[8];
    #pragma unroll
    for (int k = 0; k < 8; ++k) c[k] = __shfl(a[k], q);
    int rs = lane & 7;
    float v3 = (rs == 0) ? c[0] : (rs == 1) ? c[1] : (rs == 2) ? c[2] :
               (rs == 3) ? c[3] : (rs == 4) ? c[4] : (rs == 5) ? c[5] :
               (rs == 6) ? c[6] : c[7];

    float v0 = bf2f(h0[base]), v1 = bf2f(f1[base]), v2 = bf2f(f2[base]);
    float alo = att[lane], ahi = att[64 + lane];

    float p0 = v0 * alo;
    float q0 = v0 * ahi;
    float q1 = v1 * ahi;
    float q2 = v2 * ahi;
    float q3 = v3 * ahi;
    #pragma unroll
    for (int off = 32; off > 0; off >>= 1) {
        p0 += __shfl_xor(p0, off);
        q0 += __shfl_xor(q0, off);
        q1 += __shfl_xor(q1, off);
        q2 += __shfl_xor(q2, off);
        q3 += __shfl_xor(q3, off);
    }
    float s0 = p0 + q0, s1 = p0 + q1, s2 = p0 + q2, s3 = p0 + q3;
    s0 = s0 > 0.f ? s0 : 0.2f * s0;
    s1 = s1 > 0.f ? s1 : 0.2f * s1;
    s2 = s2 > 0.f ? s2 : 0.2f * s2;
    s3 = s3 > 0.f ? s3 : 0.2f * s3;
    float m = fmaxf(fmaxf(s0, s1), fmaxf(s2, s3));
    float e0 = expf(s0 - m), e1 = expf(s1 - m), e2 = expf(s2 - m), e3 = expf(s3 - m);
    float inv = 1.f / (e0 + e1 + e2 + e3);
    float o = (e0 * v0 + e1 * v1 + e2 * v2 + e3 * v3) * inv;

    float r = (MODE == 0) ? res[base] : v0;
    o += r + bias[lane];
    if (MODE == 0) o = o > 0.f ? o : expm1f(o);
    out[base] = o;
}

extern "C" void kernel_launch(void* const* d_in, const int* in_sizes, int n_in,
                              void* d_out, int out_size, void* d_ws, size_t ws_size,
                              hipStream_t stream)
{
    const float* x     = (const float*)d_in[0];
    const int*   ei    = (const int*)  d_in[1];
    const float* W1    = (const float*)d_in[2];
    const float* att1  = (const float*)d_in[3];
    const float* bias1 = (const float*)d_in[4];
    const float* resW1 = (const float*)d_in[5];
    const float* W2    = (const float*)d_in[6];
    const float* att2  = (const float*)d_in[7];
    const float* bias2 = (const float*)d_in[8];

    const int N_ = in_sizes[0] / 128;
    const int E_ = in_sizes[1] / 2;
    const int* src = ei;
    const int* dst = ei + E_;

    float* out = (float*)d_out;
    size_t S = (size_t)N_ * 64;
    unsigned short* h0 = (unsigned short*)d_ws;          // S bf16
    unsigned short* f1 = h0 + S;                         // S bf16
    unsigned short* f2 = f1 + S;                         // S bf16
    int* rowptr = (int*)(f2 + S);                        // N+1
    int* col    = rowptr + (N_ + 1);                     // E

    const int NB    = (E_ + EPB - 1) / EPB;              // partition blocks (<=256)
    const int NBUCK = (N_ + 255) / 256;                  // dst buckets

    // aliases (consumed before f1 is first written by the hops)
    unsigned int* packed = (unsigned int*)f1;            // E uints
    int* table = (int*)(col + E_);                       // 256*NB
    int* exclT = table + 256 * NB;                       // 256*NB
    int* bsumT = exclT + 256 * NB;                       // 256
    int* bofsT = bsumT + 256;                            // 256
    unsigned short* w1b = (unsigned short*)(bofsT + 256); // 128*128 bf16
    unsigned short* w2b = w1b + 16384;                    // 64*64 bf16

    dim3 blk(256);
    int grid_g    = (N_ + 63) / 64;
    int node_grid = (N_ + 3) / 4;
    int nT        = 256 * NB;
    int nbT       = (nT + 255) / 256;                    // == NB

    // ---------------- weight conversion + CSR build ----------------
    convert_w_kernel<<<80, blk, 0, stream>>>(W1, resW1, W2, w1b, w2b);
    part_hist_kernel<<<NB, blk, 0, stream>>>(dst, table, E_, NB);
    scanA_kernel<<<nbT, blk, 0, stream>>>(table, exclT, bsumT, nT);
    scanB_kernel<<<1, blk, 0, stream>>>(bsumT, bofsT, nbT);
    part_scatter_kernel<<<NB, blk, 0, stream>>>(src, dst, exclT, bofsT, packed, E_, NB);
    bucket_build_kernel<<<NBUCK, blk, 0, stream>>>(packed, exclT, bofsT, rowptr, col,
                                                   E_, NB, N_);

    // ---------------- layer 1 ----------------
    gemm_l1_mfma<<<grid_g, blk, 0, stream>>>(x, w1b, h0, out, N_);
    hop_csr_kernel<<<node_grid, blk, 0, stream>>>(h0, f1, rowptr, col, N_);
    hop_csr_kernel<<<node_grid, blk, 0, stream>>>(f1, f2, rowptr, col, N_);
    hop3_combine_kernel<0><<<node_grid, blk, 0, stream>>>(h0, f1, f2, out, att1, bias1, out,
                                                          rowptr, col, N_);

    // ---------------- layer 2 ----------------
    gemm_l2_mfma<<<grid_g, blk, 0, stream>>>(out, w2b, h0, N_);
    hop_csr_kernel<<<node_grid, blk, 0, stream>>>(h0, f1, rowptr, col, N_);
    hop_csr_kernel<<<node_grid, blk, 0, stream>>>(f1, f2, rowptr, col, N_);
    hop3_combine_kernel<1><<<node_grid, blk, 0, stream>>>(h0, f1, f2, nullptr, att2, bias2, out,
                                                          rowptr, col, N_);
}

// Round 9
// 212.472 us; speedup vs baseline: 1.1688x; 1.0342x over previous
//
#include <hip/hip_runtime.h>
#include <math.h>

// ---------------------------------------------------------------------------
// AGDN via CSR-gather, bf16 propagated features.
//   GEMMs: bf16 MFMA (mfma_f32_16x16x32_bf16), fp32 accum.
//   CSR build: part_hist -> scanA/B -> part_scatter -> bucket_build (LDS).
//   Hops: wave-per-node, 8 lanes/edge uint4 bf16 gather, f32x2 (pk_add) accum.
//   hop3+combine: octet-per-lane scores/output (3-level reduces, lane-local
//   weighted sum, vectorized row IO), __expf fast softmax.
// ---------------------------------------------------------------------------

#define EPB 4096     // edges per partition block
#define CAP 8192     // LDS col capacity per bucket (avg ~4096)

typedef __attribute__((ext_vector_type(8))) short bf16x8;
typedef __attribute__((ext_vector_type(4))) float f32x4;
typedef __attribute__((ext_vector_type(2))) float f32x2;

__device__ __forceinline__ float bf2f(unsigned short u)
{
    unsigned int t = ((unsigned int)u) << 16;
    return __builtin_bit_cast(float, t);
}
__device__ __forceinline__ unsigned short f2bf(float f)
{
    unsigned int t = __builtin_bit_cast(unsigned int, f);
    t += 0x7FFFu + ((t >> 16) & 1u);          // round-to-nearest-even
    return (unsigned short)(t >> 16);
}
__device__ __forceinline__ float bflo(unsigned int u)
{
    return __builtin_bit_cast(float, u << 16);
}
__device__ __forceinline__ float bfhi(unsigned int u)
{
    return __builtin_bit_cast(float, u & 0xFFFF0000u);
}
__device__ __forceinline__ f32x2 up2v(unsigned int u)
{
    f32x2 r;
    r.x = bflo(u);
    r.y = bfhi(u);
    return r;
}

// ---------------- weight pre-conversion (fp32 -> bf16, once) ---------------
__global__ __launch_bounds__(256)
void convert_w_kernel(const float* __restrict__ W1, const float* __restrict__ Wres,
                      const float* __restrict__ W2,
                      unsigned short* __restrict__ w1b, unsigned short* __restrict__ w2b)
{
    int i = blockIdx.x * 256 + threadIdx.x;
    if (i < 8192)       w1b[i] = f2bf(W1[i]);
    else if (i < 16384) w1b[i] = f2bf(Wres[i - 8192]);
    else if (i < 20480) w2b[i - 16384] = f2bf(W2[i - 16384]);
}

// ---------------- layer-1 GEMM (MFMA): 64 nodes/block, 128 outputs ---------
// w1b rows 0..63 = W1 (-> h0 bf16), rows 64..127 = resW1 (-> res fp32)
#define LD1 136   // bf16 elems per LDS row (272 B stride: 4-bank shift/row)
__global__ __launch_bounds__(256)
void gemm_l1_mfma(const float* __restrict__ x,
                  const unsigned short* __restrict__ w1b,
                  unsigned short* __restrict__ h0, float* __restrict__ res, int n)
{
    __shared__ unsigned short xs[64 * LD1];
    __shared__ unsigned short ws[128 * LD1];
    const int tid = threadIdx.x;
    const int n0 = blockIdx.x * 64;

    for (int i = tid; i < 128 * 16; i += 256) {
        int r = i >> 4, c8 = (i & 15) * 8;
        *(uint4*)&ws[r * LD1 + c8] = *(const uint4*)&w1b[r * 128 + c8];
    }
    for (int i = tid; i < 64 * 32; i += 256) {
        int r = i >> 5, c4 = (i & 31) * 4;
        int nn = n0 + r;
        float4 v = (nn < n) ? *(const float4*)&x[(size_t)nn * 128 + c4]
                            : make_float4(0.f, 0.f, 0.f, 0.f);
        uint2 o;
        o.x = (unsigned)f2bf(v.x) | ((unsigned)f2bf(v.y) << 16);
        o.y = (unsigned)f2bf(v.z) | ((unsigned)f2bf(v.w) << 16);
        *(uint2*)&xs[r * LD1 + c4] = o;
    }
    __syncthreads();

    const int wv = tid >> 6, l = tid & 63;
    const int lrow = l & 15, lk = l >> 4;     // frag row / k-group
    f32x4 acc[8] = {};
    const unsigned short* ax = &xs[(wv * 16 + lrow) * LD1 + lk * 8];
    const unsigned short* bw = &ws[lrow * LD1 + lk * 8];

    #pragma unroll
    for (int s = 0; s < 4; ++s) {            // K = 128 = 4 x 32
        bf16x8 a = *(const bf16x8*)&ax[s * 32];
        #pragma unroll
        for (int t = 0; t < 8; ++t) {        // 8 output tiles of 16
            bf16x8 b = *(const bf16x8*)&bw[(size_t)t * 16 * LD1 + s * 32];
            acc[t] = __builtin_amdgcn_mfma_f32_16x16x32_bf16(a, b, acc[t], 0, 0, 0);
        }
    }

    #pragma unroll
    for (int t = 0; t < 8; ++t) {
        #pragma unroll
        for (int r = 0; r < 4; ++r) {        // D row = lk*4 + r, col = lrow
            int node = n0 + wv * 16 + lk * 4 + r;
            if (node < n) {
                if (t < 4) h0[(size_t)node * 64 + t * 16 + lrow] = f2bf(acc[t][r]);
                else       res[(size_t)node * 64 + (t - 4) * 16 + lrow] = acc[t][r];
            }
        }
    }
}

// ---------------- layer-2 GEMM (MFMA): 64 nodes/block, 64 outputs ----------
#define LD2 72    // 144 B stride
__global__ __launch_bounds__(256)
void gemm_l2_mfma(const float* __restrict__ h,
                  const unsigned short* __restrict__ w2b,
                  unsigned short* __restrict__ h0, int n)
{
    __shared__ unsigned short xs[64 * LD2];
    __shared__ unsigned short ws[64 * LD2];
    const int tid = threadIdx.x;
    const int n0 = blockIdx.x * 64;

    for (int i = tid; i < 64 * 8; i += 256) {
        int r = i >> 3, c8 = (i & 7) * 8;
        *(uint4*)&ws[r * LD2 + c8] = *(const uint4*)&w2b[r * 64 + c8];
    }
    for (int i = tid; i < 64 * 16; i += 256) {
        int r = i >> 4, c4 = (i & 15) * 4;
        int nn = n0 + r;
        float4 v = (nn < n) ? *(const float4*)&h[(size_t)nn * 64 + c4]
                            : make_float4(0.f, 0.f, 0.f, 0.f);
        uint2 o;
        o.x = (unsigned)f2bf(v.x) | ((unsigned)f2bf(v.y) << 16);
        o.y = (unsigned)f2bf(v.z) | ((unsigned)f2bf(v.w) << 16);
        *(uint2*)&xs[r * LD2 + c4] = o;
    }
    __syncthreads();

    const int wv = tid >> 6, l = tid & 63;
    const int lrow = l & 15, lk = l >> 4;
    f32x4 acc[4] = {};
    const unsigned short* ax = &xs[(wv * 16 + lrow) * LD2 + lk * 8];
    const unsigned short* bw = &ws[lrow * LD2 + lk * 8];

    #pragma unroll
    for (int s = 0; s < 2; ++s) {            // K = 64 = 2 x 32
        bf16x8 a = *(const bf16x8*)&ax[s * 32];
        #pragma unroll
        for (int t = 0; t < 4; ++t) {
            bf16x8 b = *(const bf16x8*)&bw[(size_t)t * 16 * LD2 + s * 32];
            acc[t] = __builtin_amdgcn_mfma_f32_16x16x32_bf16(a, b, acc[t], 0, 0, 0);
        }
    }

    #pragma unroll
    for (int t = 0; t < 4; ++t) {
        #pragma unroll
        for (int r = 0; r < 4; ++r) {
            int node = n0 + wv * 16 + lk * 4 + r;
            if (node < n)
                h0[(size_t)node * 64 + t * 16 + lrow] = f2bf(acc[t][r]);
        }
    }
}

// ---------------- CSR build ----------------
__global__ __launch_bounds__(256)
void part_hist_kernel(const int* __restrict__ dst, int* __restrict__ table,
                      int E, int NB)
{
    __shared__ int h[256];
    h[threadIdx.x] = 0;
    __syncthreads();
    int base = blockIdx.x * EPB;
    for (int i = threadIdx.x; i < EPB; i += 256) {
        int e = base + i;
        if (e < E) atomicAdd(&h[((unsigned)dst[e]) >> 8], 1);
    }
    __syncthreads();
    table[threadIdx.x * NB + blockIdx.x] = h[threadIdx.x];   // bin-major
}

__global__ __launch_bounds__(256)
void scanA_kernel(const int* __restrict__ cnt, int* __restrict__ excl,
                  int* __restrict__ bsum, int n)
{
    __shared__ int sh[256];
    int i = blockIdx.x * 256 + threadIdx.x;
    int v = (i < n) ? cnt[i] : 0;
    sh[threadIdx.x] = v;
    __syncthreads();
    #pragma unroll
    for (int off = 1; off < 256; off <<= 1) {
        int t = (threadIdx.x >= off) ? sh[threadIdx.x - off] : 0;
        __syncthreads();
        sh[threadIdx.x] += t;
        __syncthreads();
    }
    if (i < n) excl[i] = sh[threadIdx.x] - v;
    if (threadIdx.x == 255) bsum[blockIdx.x] = sh[255];
}

__global__ __launch_bounds__(256)
void scanB_kernel(const int* __restrict__ bsum, int* __restrict__ bofs, int nb)
{
    __shared__ int sh[256];
    int v = (threadIdx.x < nb) ? bsum[threadIdx.x] : 0;
    sh[threadIdx.x] = v;
    __syncthreads();
    #pragma unroll
    for (int off = 1; off < 256; off <<= 1) {
        int t = (threadIdx.x >= off) ? sh[threadIdx.x - off] : 0;
        __syncthreads();
        sh[threadIdx.x] += t;
        __syncthreads();
    }
    if (threadIdx.x < nb) bofs[threadIdx.x] = sh[threadIdx.x] - v;
}

__global__ __launch_bounds__(256)
void part_scatter_kernel(const int* __restrict__ src, const int* __restrict__ dst,
                         const int* __restrict__ exclT, const int* __restrict__ bofsT,
                         unsigned int* __restrict__ packed, int E, int NB)
{
    __shared__ int lhist[256];
    __shared__ int sh[256];
    __shared__ int lexcl[256];
    __shared__ int lcur[256];
    __shared__ int gb2[256];
    __shared__ unsigned int lp[EPB];
    __shared__ unsigned char lbin[EPB];

    const int tid = threadIdx.x;
    const int base = blockIdx.x * EPB;
    const int cntE = min(EPB, E - base);

    unsigned int pv[16];
    int pb[16];
    lhist[tid] = 0;
    __syncthreads();
    #pragma unroll
    for (int it = 0; it < 16; ++it) {
        int i = it * 256 + tid;
        pv[it] = 0; pb[it] = -1;
        if (i < cntE) {
            int e = base + i;
            unsigned int p = (((unsigned)dst[e]) << 16) | (unsigned)src[e];
            pv[it] = p;
            pb[it] = (int)(p >> 24);
            atomicAdd(&lhist[pb[it]], 1);
        }
    }
    __syncthreads();
    sh[tid] = lhist[tid];
    __syncthreads();
    #pragma unroll
    for (int off = 1; off < 256; off <<= 1) {
        int t = (tid >= off) ? sh[tid - off] : 0;
        __syncthreads();
        sh[tid] += t;
        __syncthreads();
    }
    lexcl[tid] = sh[tid] - lhist[tid];
    lcur[tid] = sh[tid] - lhist[tid];
    int ti = tid * NB + blockIdx.x;
    gb2[tid] = exclT[ti] + bofsT[ti >> 8] - lexcl[tid];
    __syncthreads();
    #pragma unroll
    for (int it = 0; it < 16; ++it) {
        if (pb[it] >= 0) {
            int slot = atomicAdd(&lcur[pb[it]], 1);
            lp[slot] = pv[it];
            lbin[slot] = (unsigned char)pb[it];
        }
    }
    __syncthreads();
    for (int i = tid; i < cntE; i += 256)
        packed[gb2[lbin[i]] + i] = lp[i];
}

// fused fine stage: hist + scan + rowptr + in-LDS scatter + coalesced col out
__global__ __launch_bounds__(256)
void bucket_build_kernel(const unsigned int* __restrict__ packed,
                         const int* __restrict__ exclT, const int* __restrict__ bofsT,
                         int* __restrict__ rowptr, int* __restrict__ col,
                         int E, int NB, int N)
{
    __shared__ int h[256];
    __shared__ int sh[256];
    __shared__ int lcur[256];
    __shared__ int colL[CAP];

    const int b = blockIdx.x;
    const int t = threadIdx.x;
    int i0 = exclT[b * NB] + bofsT[(b * NB) >> 8];
    int bn = (b + 1) * NB;
    int i1 = exclT[bn] + bofsT[bn >> 8];

    h[t] = 0;
    __syncthreads();
    for (int i = i0 + t; i < i1; i += 256)
        atomicAdd(&h[(packed[i] >> 16) & 255], 1);
    __syncthreads();
    sh[t] = h[t];
    __syncthreads();
    #pragma unroll
    for (int off = 1; off < 256; off <<= 1) {
        int v = (t >= off) ? sh[t - off] : 0;
        __syncthreads();
        sh[t] += v;
        __syncthreads();
    }
    int excl = sh[t] - h[t];
    int d = b * 256 + t;
    if (d < N) rowptr[d] = i0 + excl;            // coalesced rowptr write
    if (b == gridDim.x - 1 && t == 0) rowptr[N] = E;
    lcur[t] = excl;
    __syncthreads();
    for (int i = i0 + t; i < i1; i += 256) {
        unsigned int p = packed[i];
        int lo = (p >> 16) & 255;
        int s = (int)(p & 0xFFFFu);
        int r = atomicAdd(&lcur[lo], 1);
        if (r < CAP) colL[r] = s;
        else col[i0 + r] = s;
    }
    __syncthreads();
    int cB = i1 - i0;
    for (int i = t; i < cB && i < CAP; i += 256)
        col[i0 + i] = colL[i];
}

// ---------------- hop: wave per node; 8 lanes/edge, 8 edges/instr ----------
__global__ __launch_bounds__(256)
void hop_csr_kernel(const unsigned short* __restrict__ fin,
                    unsigned short* __restrict__ fout,
                    const int* __restrict__ rowptr, const int* __restrict__ col, int n)
{
    int node = blockIdx.x * 4 + (threadIdx.x >> 6);
    if (node >= n) return;
    int lane = threadIdx.x & 63;
    int sub = lane >> 3;            // edge slot 0..7
    int fo = (lane & 7) * 8;        // feature octet start

    int beg = rowptr[node], end = rowptr[node + 1];
    int deg = end - beg;
    f32x2 ac[4] = {};
    for (int b = 0; b < deg; b += 16) {
        int e0 = beg + b + sub, e1 = e0 + 8;
        uint4 u0 = make_uint4(0, 0, 0, 0), u1 = make_uint4(0, 0, 0, 0);
        if (e0 < end) { int s = col[e0]; u0 = *(const uint4*)&fin[(size_t)s * 64 + fo]; }
        if (e1 < end) { int s = col[e1]; u1 = *(const uint4*)&fin[(size_t)s * 64 + fo]; }
        ac[0] += up2v(u0.x); ac[1] += up2v(u0.y);
        ac[2] += up2v(u0.z); ac[3] += up2v(u0.w);
        ac[0] += up2v(u1.x); ac[1] += up2v(u1.y);
        ac[2] += up2v(u1.z); ac[3] += up2v(u1.w);
    }
    float a[8] = {ac[0].x, ac[0].y, ac[1].x, ac[1].y,
                  ac[2].x, ac[2].y, ac[3].x, ac[3].y};
    #pragma unroll
    for (int off = 8; off <= 32; off <<= 1)
        #pragma unroll
        for (int k = 0; k < 8; ++k)
            a[k] += __shfl_xor(a[k], off);
    if (sub == 0) {
        uint4 o;
        o.x = (unsigned)f2bf(a[0]) | ((unsigned)f2bf(a[1]) << 16);
        o.y = (unsigned)f2bf(a[2]) | ((unsigned)f2bf(a[3]) << 16);
        o.z = (unsigned)f2bf(a[4]) | ((unsigned)f2bf(a[5]) << 16);
        o.w = (unsigned)f2bf(a[6]) | ((unsigned)f2bf(a[7]) << 16);
        *(uint4*)&fout[(size_t)node * 64 + fo] = o;
    }
}

// ---------------- 3rd hop fused with attention combine (octet layout) ------
// MODE 0: layer 1 (res from fp32 res buffer, apply ELU); MODE 1: layer 2.
template<int MODE>
__global__ __launch_bounds__(256)
void hop3_combine_kernel(const unsigned short* __restrict__ h0,
                         const unsigned short* __restrict__ f1,
                         const unsigned short* __restrict__ f2,
                         const float* __restrict__ res, const float* __restrict__ att,
                         const float* __restrict__ bias, float* __restrict__ out,
                         const int* __restrict__ rowptr, const int* __restrict__ col, int n)
{
    int node = blockIdx.x * 4 + (threadIdx.x >> 6);
    if (node >= n) return;
    int lane = threadIdx.x & 63;
    int sub = lane >> 3;            // edge slot 0..7
    int fo = (lane & 7) * 8;        // feature octet start
    size_t rbase = (size_t)node * 64 + fo;

    // f3 octet = gather-sum of f2 rows
    int beg = rowptr[node], end = rowptr[node + 1];
    int deg = end - beg;
    f32x2 ac[4] = {};
    for (int b = 0; b < deg; b += 16) {
        int e0 = beg + b + sub, e1 = e0 + 8;
        uint4 u0 = make_uint4(0, 0, 0, 0), u1 = make_uint4(0, 0, 0, 0);
        if (e0 < end) { int s = col[e0]; u0 = *(const uint4*)&f2[(size_t)s * 64 + fo]; }
        if (e1 < end) { int s = col[e1]; u1 = *(const uint4*)&f2[(size_t)s * 64 + fo]; }
        ac[0] += up2v(u0.x); ac[1] += up2v(u0.y);
        ac[2] += up2v(u0.z); ac[3] += up2v(u0.w);
        ac[0] += up2v(u1.x); ac[1] += up2v(u1.y);
        ac[2] += up2v(u1.z); ac[3] += up2v(u1.w);
    }
    float a[8] = {ac[0].x, ac[0].y, ac[1].x, ac[1].y,
                  ac[2].x, ac[2].y, ac[3].x, ac[3].y};
    #pragma unroll
    for (int off = 8; off <= 32; off <<= 1)
        #pragma unroll
        for (int k = 0; k < 8; ++k)
            a[k] += __shfl_xor(a[k], off);
    // now every lane holds the full f3 octet for features fo..fo+7

    // octet rows of h0, f1, f2 (vectorized; one 128B line per wave per array)
    uint4 r0 = *(const uint4*)&h0[rbase];
    uint4 r1 = *(const uint4*)&f1[rbase];
    uint4 r2 = *(const uint4*)&f2[rbase];
    float v0f[8] = {bflo(r0.x), bfhi(r0.x), bflo(r0.y), bfhi(r0.y),
                    bflo(r0.z), bfhi(r0.z), bflo(r0.w), bfhi(r0.w)};
    float v1f[8] = {bflo(r1.x), bfhi(r1.x), bflo(r1.y), bfhi(r1.y),
                    bflo(r1.z), bfhi(r1.z), bflo(r1.w), bfhi(r1.w)};
    float v2f[8] = {bflo(r2.x), bfhi(r2.x), bflo(r2.y), bfhi(r2.y),
                    bflo(r2.z), bfhi(r2.z), bflo(r2.w), bfhi(r2.w)};

    float4 alo0 = *(const float4*)&att[fo];
    float4 alo1 = *(const float4*)&att[fo + 4];
    float4 ahi0 = *(const float4*)&att[64 + fo];
    float4 ahi1 = *(const float4*)&att[64 + fo + 4];
    float alo[8] = {alo0.x, alo0.y, alo0.z, alo0.w, alo1.x, alo1.y, alo1.z, alo1.w};
    float ahi[8] = {ahi0.x, ahi0.y, ahi0.z, ahi0.w, ahi1.x, ahi1.y, ahi1.z, ahi1.w};

    // per-octet partial dot products, then 3-level reduce over octets
    float p0 = 0.f, q0 = 0.f, q1 = 0.f, q2 = 0.f, q3 = 0.f;
    #pragma unroll
    for (int j = 0; j < 8; ++j) {
        p0 += v0f[j] * alo[j];
        q0 += v0f[j] * ahi[j];
        q1 += v1f[j] * ahi[j];
        q2 += v2f[j] * ahi[j];
        q3 += a[j]   * ahi[j];
    }
    #pragma unroll
    for (int off = 1; off <= 4; off <<= 1) {
        p0 += __shfl_xor(p0, off);
        q0 += __shfl_xor(q0, off);
        q1 += __shfl_xor(q1, off);
        q2 += __shfl_xor(q2, off);
        q3 += __shfl_xor(q3, off);
    }

    float s0 = p0 + q0, s1 = p0 + q1, s2 = p0 + q2, s3 = p0 + q3;
    s0 = s0 > 0.f ? s0 : 0.2f * s0;
    s1 = s1 > 0.f ? s1 : 0.2f * s1;
    s2 = s2 > 0.f ? s2 : 0.2f * s2;
    s3 = s3 > 0.f ? s3 : 0.2f * s3;
    float m = fmaxf(fmaxf(s0, s1), fmaxf(s2, s3));
    float E0 = __expf(s0 - m), E1 = __expf(s1 - m);
    float E2 = __expf(s2 - m), E3 = __expf(s3 - m);
    float inv = 1.f / (E0 + E1 + E2 + E3);
    float w0 = E0 * inv, w1 = E1 * inv, w2 = E2 * inv, w3 = E3 * inv;

    // lane-local weighted sum + residual + bias (+ ELU)
    float rsv[8];
    if (MODE == 0) {
        float4 ra = *(const float4*)&res[rbase];
        float4 rb = *(const float4*)&res[rbase + 4];
        rsv[0] = ra.x; rsv[1] = ra.y; rsv[2] = ra.z; rsv[3] = ra.w;
        rsv[4] = rb.x; rsv[5] = rb.y; rsv[6] = rb.z; rsv[7] = rb.w;
    } else {
        #pragma unroll
        for (int j = 0; j < 8; ++j) rsv[j] = v0f[j];
    }
    float4 ba = *(const float4*)&bias[fo];
    float4 bb = *(const float4*)&bias[fo + 4];
    float bi[8] = {ba.x, ba.y, ba.z, ba.w, bb.x, bb.y, bb.z, bb.w};

    float o[8];
    #pragma unroll
    for (int j = 0; j < 8; ++j) {
        float v = w0 * v0f[j] + w1 * v1f[j] + w2 * v2f[j] + w3 * a[j];
        v += rsv[j] + bi[j];
        if (MODE == 0) v = v > 0.f ? v : __expf(v) - 1.f;   // ELU(alpha=1)
        o[j] = v;
    }
    if (sub == 0) {
        *(float4*)&out[rbase]     = make_float4(o[0], o[1], o[2], o[3]);
        *(float4*)&out[rbase + 4] = make_float4(o[4], o[5], o[6], o[7]);
    }
}

extern "C" void kernel_launch(void* const* d_in, const int* in_sizes, int n_in,
                              void* d_out, int out_size, void* d_ws, size_t ws_size,
                              hipStream_t stream)
{
    const float* x     = (const float*)d_in[0];
    const int*   ei    = (const int*)  d_in[1];
    const float* W1    = (const float*)d_in[2];
    const float* att1  = (const float*)d_in[3];
    const float* bias1 = (const float*)d_in[4];
    const float* resW1 = (const float*)d_in[5];
    const float* W2    = (const float*)d_in[6];
    const float* att2  = (const float*)d_in[7];
    const float* bias2 = (const float*)d_in[8];

    const int N_ = in_sizes[0] / 128;
    const int E_ = in_sizes[1] / 2;
    const int* src = ei;
    const int* dst = ei + E_;

    float* out = (float*)d_out;
    size_t S = (size_t)N_ * 64;
    unsigned short* h0 = (unsigned short*)d_ws;          // S bf16
    unsigned short* f1 = h0 + S;                         // S bf16
    unsigned short* f2 = f1 + S;                         // S bf16
    int* rowptr = (int*)(f2 + S);                        // N+1
    int* col    = rowptr + (N_ + 1);                     // E

    const int NB    = (E_ + EPB - 1) / EPB;              // partition blocks (<=256)
    const int NBUCK = (N_ + 255) / 256;                  // dst buckets

    // aliases (consumed before f1 is first written by the hops)
    unsigned int* packed = (unsigned int*)f1;            // E uints
    int* table = (int*)(col + E_);                       // 256*NB
    int* exclT = table + 256 * NB;                       // 256*NB
    int* bsumT = exclT + 256 * NB;                       // 256
    int* bofsT = bsumT + 256;                            // 256
    unsigned short* w1b = (unsigned short*)(bofsT + 256); // 128*128 bf16
    unsigned short* w2b = w1b + 16384;                    // 64*64 bf16

    dim3 blk(256);
    int grid_g    = (N_ + 63) / 64;
    int node_grid = (N_ + 3) / 4;
    int nT        = 256 * NB;
    int nbT       = (nT + 255) / 256;                    // == NB

    // ---------------- weight conversion + CSR build ----------------
    convert_w_kernel<<<80, blk, 0, stream>>>(W1, resW1, W2, w1b, w2b);
    part_hist_kernel<<<NB, blk, 0, stream>>>(dst, table, E_, NB);
    scanA_kernel<<<nbT, blk, 0, stream>>>(table, exclT, bsumT, nT);
    scanB_kernel<<<1, blk, 0, stream>>>(bsumT, bofsT, nbT);
    part_scatter_kernel<<<NB, blk, 0, stream>>>(src, dst, exclT, bofsT, packed, E_, NB);
    bucket_build_kernel<<<NBUCK, blk, 0, stream>>>(packed, exclT, bofsT, rowptr, col,
                                                   E_, NB, N_);

    // ---------------- layer 1 ----------------
    gemm_l1_mfma<<<grid_g, blk, 0, stream>>>(x, w1b, h0, out, N_);
    hop_csr_kernel<<<node_grid, blk, 0, stream>>>(h0, f1, rowptr, col, N_);
    hop_csr_kernel<<<node_grid, blk, 0, stream>>>(f1, f2, rowptr, col, N_);
    hop3_combine_kernel<0><<<node_grid, blk, 0, stream>>>(h0, f1, f2, out, att1, bias1, out,
                                                          rowptr, col, N_);

    // ---------------- layer 2 ----------------
    gemm_l2_mfma<<<grid_g, blk, 0, stream>>>(out, w2b, h0, N_);
    hop_csr_kernel<<<node_grid, blk, 0, stream>>>(h0, f1, rowptr, col, N_);
    hop_csr_kernel<<<node_grid, blk, 0, stream>>>(f1, f2, rowptr, col, N_);
    hop3_combine_kernel<1><<<node_grid, blk, 0, stream>>>(h0, f1, f2, nullptr, att2, bias2, out,
                                                          rowptr, col, N_);
}

// Round 10
// 179.674 us; speedup vs baseline: 1.3821x; 1.1825x over previous
//
#include <hip/hip_runtime.h>
#include <math.h>

// ---------------------------------------------------------------------------
// AGDN via CSR-gather, bf16 propagated features.
//   GEMMs: bf16 MFMA (mfma_f32_16x16x32_bf16), fp32 accum.
//   CSR build: part_hist(+w convert) -> scanA/B -> part_scatter ->
//     bucket_build (single global pass; packed staged in LDS).
//   Hops/combines: TWO nodes per wave (32-lane half each, 4 edge-slots x
//     8 octets), uint4 bf16 gather, 2-level sub-reduce, fp32 accum.
// ---------------------------------------------------------------------------

#define EPB 4096     // edges per partition block
#define CAP 8192     // LDS col capacity per bucket (avg ~4096)

typedef __attribute__((ext_vector_type(8))) short bf16x8;
typedef __attribute__((ext_vector_type(4))) float f32x4;
typedef __attribute__((ext_vector_type(2))) float f32x2;

__device__ __forceinline__ unsigned short f2bf(float f)
{
    unsigned int t = __builtin_bit_cast(unsigned int, f);
    t += 0x7FFFu + ((t >> 16) & 1u);          // round-to-nearest-even
    return (unsigned short)(t >> 16);
}
__device__ __forceinline__ float bflo(unsigned int u)
{
    return __builtin_bit_cast(float, u << 16);
}
__device__ __forceinline__ float bfhi(unsigned int u)
{
    return __builtin_bit_cast(float, u & 0xFFFF0000u);
}
__device__ __forceinline__ f32x2 up2v(unsigned int u)
{
    f32x2 r;
    r.x = bflo(u);
    r.y = bfhi(u);
    return r;
}

// ---------------- layer-1 GEMM (MFMA): 64 nodes/block, 128 outputs ---------
// w1b rows 0..63 = W1 (-> h0 bf16), rows 64..127 = resW1 (-> res fp32)
#define LD1 136   // bf16 elems per LDS row (272 B stride: 4-bank shift/row)
__global__ __launch_bounds__(256)
void gemm_l1_mfma(const float* __restrict__ x,
                  const unsigned short* __restrict__ w1b,
                  unsigned short* __restrict__ h0, float* __restrict__ res, int n)
{
    __shared__ unsigned short xs[64 * LD1];
    __shared__ unsigned short ws[128 * LD1];
    const int tid = threadIdx.x;
    const int n0 = blockIdx.x * 64;

    for (int i = tid; i < 128 * 16; i += 256) {
        int r = i >> 4, c8 = (i & 15) * 8;
        *(uint4*)&ws[r * LD1 + c8] = *(const uint4*)&w1b[r * 128 + c8];
    }
    for (int i = tid; i < 64 * 32; i += 256) {
        int r = i >> 5, c4 = (i & 31) * 4;
        int nn = n0 + r;
        float4 v = (nn < n) ? *(const float4*)&x[(size_t)nn * 128 + c4]
                            : make_float4(0.f, 0.f, 0.f, 0.f);
        uint2 o;
        o.x = (unsigned)f2bf(v.x) | ((unsigned)f2bf(v.y) << 16);
        o.y = (unsigned)f2bf(v.z) | ((unsigned)f2bf(v.w) << 16);
        *(uint2*)&xs[r * LD1 + c4] = o;
    }
    __syncthreads();

    const int wv = tid >> 6, l = tid & 63;
    const int lrow = l & 15, lk = l >> 4;     // frag row / k-group
    f32x4 acc[8] = {};
    const unsigned short* ax = &xs[(wv * 16 + lrow) * LD1 + lk * 8];
    const unsigned short* bw = &ws[lrow * LD1 + lk * 8];

    #pragma unroll
    for (int s = 0; s < 4; ++s) {            // K = 128 = 4 x 32
        bf16x8 a = *(const bf16x8*)&ax[s * 32];
        #pragma unroll
        for (int t = 0; t < 8; ++t) {        // 8 output tiles of 16
            bf16x8 b = *(const bf16x8*)&bw[(size_t)t * 16 * LD1 + s * 32];
            acc[t] = __builtin_amdgcn_mfma_f32_16x16x32_bf16(a, b, acc[t], 0, 0, 0);
        }
    }

    #pragma unroll
    for (int t = 0; t < 8; ++t) {
        #pragma unroll
        for (int r = 0; r < 4; ++r) {        // D row = lk*4 + r, col = lrow
            int node = n0 + wv * 16 + lk * 4 + r;
            if (node < n) {
                if (t < 4) h0[(size_t)node * 64 + t * 16 + lrow] = f2bf(acc[t][r]);
                else       res[(size_t)node * 64 + (t - 4) * 16 + lrow] = acc[t][r];
            }
        }
    }
}

// ---------------- layer-2 GEMM (MFMA): 64 nodes/block, 64 outputs ----------
#define LD2 72    // 144 B stride
__global__ __launch_bounds__(256)
void gemm_l2_mfma(const float* __restrict__ h,
                  const unsigned short* __restrict__ w2b,
                  unsigned short* __restrict__ h0, int n)
{
    __shared__ unsigned short xs[64 * LD2];
    __shared__ unsigned short ws[64 * LD2];
    const int tid = threadIdx.x;
    const int n0 = blockIdx.x * 64;

    for (int i = tid; i < 64 * 8; i += 256) {
        int r = i >> 3, c8 = (i & 7) * 8;
        *(uint4*)&ws[r * LD2 + c8] = *(const uint4*)&w2b[r * 64 + c8];
    }
    for (int i = tid; i < 64 * 16; i += 256) {
        int r = i >> 4, c4 = (i & 15) * 4;
        int nn = n0 + r;
        float4 v = (nn < n) ? *(const float4*)&h[(size_t)nn * 64 + c4]
                            : make_float4(0.f, 0.f, 0.f, 0.f);
        uint2 o;
        o.x = (unsigned)f2bf(v.x) | ((unsigned)f2bf(v.y) << 16);
        o.y = (unsigned)f2bf(v.z) | ((unsigned)f2bf(v.w) << 16);
        *(uint2*)&xs[r * LD2 + c4] = o;
    }
    __syncthreads();

    const int wv = tid >> 6, l = tid & 63;
    const int lrow = l & 15, lk = l >> 4;
    f32x4 acc[4] = {};
    const unsigned short* ax = &xs[(wv * 16 + lrow) * LD2 + lk * 8];
    const unsigned short* bw = &ws[lrow * LD2 + lk * 8];

    #pragma unroll
    for (int s = 0; s < 2; ++s) {            // K = 64 = 2 x 32
        bf16x8 a = *(const bf16x8*)&ax[s * 32];
        #pragma unroll
        for (int t = 0; t < 4; ++t) {
            bf16x8 b = *(const bf16x8*)&bw[(size_t)t * 16 * LD2 + s * 32];
            acc[t] = __builtin_amdgcn_mfma_f32_16x16x32_bf16(a, b, acc[t], 0, 0, 0);
        }
    }

    #pragma unroll
    for (int t = 0; t < 4; ++t) {
        #pragma unroll
        for (int r = 0; r < 4; ++r) {
            int node = n0 + wv * 16 + lk * 4 + r;
            if (node < n)
                h0[(size_t)node * 64 + t * 16 + lrow] = f2bf(acc[t][r]);
        }
    }
}

// ---------------- CSR build ----------------
// coarse hist (+ fused weight conversion: NB*256 threads cover 20480 elems)
__global__ __launch_bounds__(256)
void part_hist_kernel(const int* __restrict__ dst, int* __restrict__ table,
                      int E, int NB,
                      const float* __restrict__ W1, const float* __restrict__ Wres,
                      const float* __restrict__ W2,
                      unsigned short* __restrict__ w1b, unsigned short* __restrict__ w2b)
{
    int gi = blockIdx.x * 256 + threadIdx.x;
    if (gi < 8192)       w1b[gi] = f2bf(W1[gi]);
    else if (gi < 16384) w1b[gi] = f2bf(Wres[gi - 8192]);
    else if (gi < 20480) w2b[gi - 16384] = f2bf(W2[gi - 16384]);

    __shared__ int h[256];
    h[threadIdx.x] = 0;
    __syncthreads();
    int base = blockIdx.x * EPB;
    for (int i = threadIdx.x; i < EPB; i += 256) {
        int e = base + i;
        if (e < E) atomicAdd(&h[((unsigned)dst[e]) >> 8], 1);
    }
    __syncthreads();
    table[threadIdx.x * NB + blockIdx.x] = h[threadIdx.x];   // bin-major
}

__global__ __launch_bounds__(256)
void scanA_kernel(const int* __restrict__ cnt, int* __restrict__ excl,
                  int* __restrict__ bsum, int n)
{
    __shared__ int sh[256];
    int i = blockIdx.x * 256 + threadIdx.x;
    int v = (i < n) ? cnt[i] : 0;
    sh[threadIdx.x] = v;
    __syncthreads();
    #pragma unroll
    for (int off = 1; off < 256; off <<= 1) {
        int t = (threadIdx.x >= off) ? sh[threadIdx.x - off] : 0;
        __syncthreads();
        sh[threadIdx.x] += t;
        __syncthreads();
    }
    if (i < n) excl[i] = sh[threadIdx.x] - v;
    if (threadIdx.x == 255) bsum[blockIdx.x] = sh[255];
}

__global__ __launch_bounds__(256)
void scanB_kernel(const int* __restrict__ bsum, int* __restrict__ bofs, int nb)
{
    __shared__ int sh[256];
    int v = (threadIdx.x < nb) ? bsum[threadIdx.x] : 0;
    sh[threadIdx.x] = v;
    __syncthreads();
    #pragma unroll
    for (int off = 1; off < 256; off <<= 1) {
        int t = (threadIdx.x >= off) ? sh[threadIdx.x - off] : 0;
        __syncthreads();
        sh[threadIdx.x] += t;
        __syncthreads();
    }
    if (threadIdx.x < nb) bofs[threadIdx.x] = sh[threadIdx.x] - v;
}

__global__ __launch_bounds__(256)
void part_scatter_kernel(const int* __restrict__ src, const int* __restrict__ dst,
                         const int* __restrict__ exclT, const int* __restrict__ bofsT,
                         unsigned int* __restrict__ packed, int E, int NB)
{
    __shared__ int lhist[256];
    __shared__ int sh[256];
    __shared__ int lexcl[256];
    __shared__ int lcur[256];
    __shared__ int gb2[256];
    __shared__ unsigned int lp[EPB];
    __shared__ unsigned char lbin[EPB];

    const int tid = threadIdx.x;
    const int base = blockIdx.x * EPB;
    const int cntE = min(EPB, E - base);

    unsigned int pv[16];
    int pb[16];
    lhist[tid] = 0;
    __syncthreads();
    #pragma unroll
    for (int it = 0; it < 16; ++it) {
        int i = it * 256 + tid;
        pv[it] = 0; pb[it] = -1;
        if (i < cntE) {
            int e = base + i;
            unsigned int p = (((unsigned)dst[e]) << 16) | (unsigned)src[e];
            pv[it] = p;
            pb[it] = (int)(p >> 24);
            atomicAdd(&lhist[pb[it]], 1);
        }
    }
    __syncthreads();
    sh[tid] = lhist[tid];
    __syncthreads();
    #pragma unroll
    for (int off = 1; off < 256; off <<= 1) {
        int t = (tid >= off) ? sh[tid - off] : 0;
        __syncthreads();
        sh[tid] += t;
        __syncthreads();
    }
    lexcl[tid] = sh[tid] - lhist[tid];
    lcur[tid] = sh[tid] - lhist[tid];
    int ti = tid * NB + blockIdx.x;
    gb2[tid] = exclT[ti] + bofsT[ti >> 8] - lexcl[tid];
    __syncthreads();
    #pragma unroll
    for (int it = 0; it < 16; ++it) {
        if (pb[it] >= 0) {
            int slot = atomicAdd(&lcur[pb[it]], 1);
            lp[slot] = pv[it];
            lbin[slot] = (unsigned char)pb[it];
        }
    }
    __syncthreads();
    for (int i = tid; i < cntE; i += 256)
        packed[gb2[lbin[i]] + i] = lp[i];
}

// fused fine stage, single global pass: stage packed run in LDS, then
// hist + scan + rowptr + scatter + coalesced col copy-out.
__global__ __launch_bounds__(256)
void bucket_build_kernel(const unsigned int* __restrict__ packed,
                         const int* __restrict__ exclT, const int* __restrict__ bofsT,
                         int* __restrict__ rowptr, int* __restrict__ col,
                         int E, int NB, int N)
{
    __shared__ int h[256];
    __shared__ int sh[256];
    __shared__ int lcur[256];
    __shared__ unsigned int lp[CAP];
    __shared__ unsigned short colS[CAP];

    const int b = blockIdx.x;
    const int t = threadIdx.x;
    int i0 = exclT[b * NB] + bofsT[(b * NB) >> 8];
    int bn = (b + 1) * NB;
    int i1 = exclT[bn] + bofsT[bn >> 8];
    int cB = i1 - i0;

    h[t] = 0;
    __syncthreads();
    for (int i = t; i < cB; i += 256) {
        unsigned int p = packed[i0 + i];
        if (i < CAP) lp[i] = p;
        atomicAdd(&h[(p >> 16) & 255], 1);
    }
    __syncthreads();
    sh[t] = h[t];
    __syncthreads();
    #pragma unroll
    for (int off = 1; off < 256; off <<= 1) {
        int v = (t >= off) ? sh[t - off] : 0;
        __syncthreads();
        sh[t] += v;
        __syncthreads();
    }
    int excl = sh[t] - h[t];
    int d = b * 256 + t;
    if (d < N) rowptr[d] = i0 + excl;            // coalesced rowptr write
    if (b == gridDim.x - 1 && t == 0) rowptr[N] = E;
    lcur[t] = excl;
    __syncthreads();
    for (int i = t; i < cB; i += 256) {
        unsigned int p = (i < CAP) ? lp[i] : packed[i0 + i];
        int lo = (p >> 16) & 255;
        int r = atomicAdd(&lcur[lo], 1);
        if (r < CAP) colS[r] = (unsigned short)(p & 0xFFFFu);
        else col[i0 + r] = (int)(p & 0xFFFFu);
    }
    __syncthreads();
    for (int i = t; i < cB && i < CAP; i += 256)
        col[i0 + i] = (int)colS[i];
}

// ---------------- hop: TWO nodes per wave; 4 edge-slots x 8 octets ---------
__global__ __launch_bounds__(256)
void hop_csr_kernel(const unsigned short* __restrict__ fin,
                    unsigned short* __restrict__ fout,
                    const int* __restrict__ rowptr, const int* __restrict__ col, int n)
{
    int lane = threadIdx.x & 63;
    int node = blockIdx.x * 8 + ((threadIdx.x >> 6) << 1) + (lane >> 5);
    if (node >= n) return;
    int sub = (lane >> 3) & 3;      // edge slot 0..3
    int fo = (lane & 7) * 8;        // feature octet start

    int beg = rowptr[node], end = rowptr[node + 1];
    f32x2 ac[4] = {};
    for (int b = beg + sub; b < end; b += 8) {
        int s0 = col[b];
        uint4 u0 = *(const uint4*)&fin[(size_t)s0 * 64 + fo];
        uint4 u1 = make_uint4(0, 0, 0, 0);
        int e1 = b + 4;
        if (e1 < end) { int s1 = col[e1]; u1 = *(const uint4*)&fin[(size_t)s1 * 64 + fo]; }
        ac[0] += up2v(u0.x); ac[1] += up2v(u0.y);
        ac[2] += up2v(u0.z); ac[3] += up2v(u0.w);
        ac[0] += up2v(u1.x); ac[1] += up2v(u1.y);
        ac[2] += up2v(u1.z); ac[3] += up2v(u1.w);
    }
    float a[8] = {ac[0].x, ac[0].y, ac[1].x, ac[1].y,
                  ac[2].x, ac[2].y, ac[3].x, ac[3].y};
    #pragma unroll
    for (int off = 8; off <= 16; off <<= 1)        // reduce over 4 sub-slots
        #pragma unroll
        for (int k = 0; k < 8; ++k)
            a[k] += __shfl_xor(a[k], off);
    if (sub == 0) {
        uint4 o;
        o.x = (unsigned)f2bf(a[0]) | ((unsigned)f2bf(a[1]) << 16);
        o.y = (unsigned)f2bf(a[2]) | ((unsigned)f2bf(a[3]) << 16);
        o.z = (unsigned)f2bf(a[4]) | ((unsigned)f2bf(a[5]) << 16);
        o.w = (unsigned)f2bf(a[6]) | ((unsigned)f2bf(a[7]) << 16);
        *(uint4*)&fout[(size_t)node * 64 + fo] = o;
    }
}

// ---------------- 3rd hop fused with attention combine (2 nodes/wave) ------
// MODE 0: layer 1 (res from fp32 res buffer, apply ELU); MODE 1: layer 2.
template<int MODE>
__global__ __launch_bounds__(256)
void hop3_combine_kernel(const unsigned short* __restrict__ h0,
                         const unsigned short* __restrict__ f1,
                         const unsigned short* __restrict__ f2,
                         const float* __restrict__ res, const float* __restrict__ att,
                         const float* __restrict__ bias, float* __restrict__ out,
                         const int* __restrict__ rowptr, const int* __restrict__ col, int n)
{
    int lane = threadIdx.x & 63;
    int node = blockIdx.x * 8 + ((threadIdx.x >> 6) << 1) + (lane >> 5);
    if (node >= n) return;
    int sub = (lane >> 3) & 3;      // edge slot 0..3
    int fo = (lane & 7) * 8;        // feature octet start
    size_t rbase = (size_t)node * 64 + fo;

    // f3 octet = gather-sum of f2 rows
    int beg = rowptr[node], end = rowptr[node + 1];
    f32x2 ac[4] = {};
    for (int b = beg + sub; b < end; b += 8) {
        int s0 = col[b];
        uint4 u0 = *(const uint4*)&f2[(size_t)s0 * 64 + fo];
        uint4 u1 = make_uint4(0, 0, 0, 0);
        int e1 = b + 4;
        if (e1 < end) { int s1 = col[e1]; u1 = *(const uint4*)&f2[(size_t)s1 * 64 + fo]; }
        ac[0] += up2v(u0.x); ac[1] += up2v(u0.y);
        ac[2] += up2v(u0.z); ac[3] += up2v(u0.w);
        ac[0] += up2v(u1.x); ac[1] += up2v(u1.y);
        ac[2] += up2v(u1.z); ac[3] += up2v(u1.w);
    }
    float a[8] = {ac[0].x, ac[0].y, ac[1].x, ac[1].y,
                  ac[2].x, ac[2].y, ac[3].x, ac[3].y};
    #pragma unroll
    for (int off = 8; off <= 16; off <<= 1)        // reduce over 4 sub-slots
        #pragma unroll
        for (int k = 0; k < 8; ++k)
            a[k] += __shfl_xor(a[k], off);
    // every lane of the 32-lane half now holds the full f3 octet for fo..fo+7

    uint4 r0 = *(const uint4*)&h0[rbase];
    uint4 r1 = *(const uint4*)&f1[rbase];
    uint4 r2 = *(const uint4*)&f2[rbase];
    float v0f[8] = {bflo(r0.x), bfhi(r0.x), bflo(r0.y), bfhi(r0.y),
                    bflo(r0.z), bfhi(r0.z), bflo(r0.w), bfhi(r0.w)};
    float v1f[8] = {bflo(r1.x), bfhi(r1.x), bflo(r1.y), bfhi(r1.y),
                    bflo(r1.z), bfhi(r1.z), bflo(r1.w), bfhi(r1.w)};
    float v2f[8] = {bflo(r2.x), bfhi(r2.x), bflo(r2.y), bfhi(r2.y),
                    bflo(r2.z), bfhi(r2.z), bflo(r2.w), bfhi(r2.w)};

    float4 alo0 = *(const float4*)&att[fo];
    float4 alo1 = *(const float4*)&att[fo + 4];
    float4 ahi0 = *(const float4*)&att[64 + fo];
    float4 ahi1 = *(const float4*)&att[64 + fo + 4];
    float alo[8] = {alo0.x, alo0.y, alo0.z, alo0.w, alo1.x, alo1.y, alo1.z, alo1.w};
    float ahi[8] = {ahi0.x, ahi0.y, ahi0.z, ahi0.w, ahi1.x, ahi1.y, ahi1.z, ahi1.w};

    // per-octet partial dot products, then 3-level reduce over octets
    float p0 = 0.f, q0 = 0.f, q1 = 0.f, q2 = 0.f, q3 = 0.f;
    #pragma unroll
    for (int j = 0; j < 8; ++j) {
        p0 += v0f[j] * alo[j];
        q0 += v0f[j] * ahi[j];
        q1 += v1f[j] * ahi[j];
        q2 += v2f[j] * ahi[j];
        q3 += a[j]   * ahi[j];
    }
    #pragma unroll
    for (int off = 1; off <= 4; off <<= 1) {
        p0 += __shfl_xor(p0, off);
        q0 += __shfl_xor(q0, off);
        q1 += __shfl_xor(q1, off);
        q2 += __shfl_xor(q2, off);
        q3 += __shfl_xor(q3, off);
    }

    float s0 = p0 + q0, s1 = p0 + q1, s2 = p0 + q2, s3 = p0 + q3;
    s0 = s0 > 0.f ? s0 : 0.2f * s0;
    s1 = s1 > 0.f ? s1 : 0.2f * s1;
    s2 = s2 > 0.f ? s2 : 0.2f * s2;
    s3 = s3 > 0.f ? s3 : 0.2f * s3;
    float m = fmaxf(fmaxf(s0, s1), fmaxf(s2, s3));
    float E0 = __expf(s0 - m), E1 = __expf(s1 - m);
    float E2 = __expf(s2 - m), E3 = __expf(s3 - m);
    float inv = 1.f / (E0 + E1 + E2 + E3);
    float w0 = E0 * inv, w1 = E1 * inv, w2 = E2 * inv, w3 = E3 * inv;

    float rsv[8];
    if (MODE == 0) {
        float4 ra = *(const float4*)&res[rbase];
        float4 rb = *(const float4*)&res[rbase + 4];
        rsv[0] = ra.x; rsv[1] = ra.y; rsv[2] = ra.z; rsv[3] = ra.w;
        rsv[4] = rb.x; rsv[5] = rb.y; rsv[6] = rb.z; rsv[7] = rb.w;
    } else {
        #pragma unroll
        for (int j = 0; j < 8; ++j) rsv[j] = v0f[j];
    }
    float4 ba = *(const float4*)&bias[fo];
    float4 bb = *(const float4*)&bias[fo + 4];
    float bi[8] = {ba.x, ba.y, ba.z, ba.w, bb.x, bb.y, bb.z, bb.w};

    float o[8];
    #pragma unroll
    for (int j = 0; j < 8; ++j) {
        float v = w0 * v0f[j] + w1 * v1f[j] + w2 * v2f[j] + w3 * a[j];
        v += rsv[j] + bi[j];
        if (MODE == 0) v = v > 0.f ? v : __expf(v) - 1.f;   // ELU(alpha=1)
        o[j] = v;
    }
    if (sub == 0) {
        *(float4*)&out[rbase]     = make_float4(o[0], o[1], o[2], o[3]);
        *(float4*)&out[rbase + 4] = make_float4(o[4], o[5], o[6], o[7]);
    }
}

extern "C" void kernel_launch(void* const* d_in, const int* in_sizes, int n_in,
                              void* d_out, int out_size, void* d_ws, size_t ws_size,
                              hipStream_t stream)
{
    const float* x     = (const float*)d_in[0];
    const int*   ei    = (const int*)  d_in[1];
    const float* W1    = (const float*)d_in[2];
    const float* att1  = (const float*)d_in[3];
    const float* bias1 = (const float*)d_in[4];
    const float* resW1 = (const float*)d_in[5];
    const float* W2    = (const float*)d_in[6];
    const float* att2  = (const float*)d_in[7];
    const float* bias2 = (const float*)d_in[8];

    const int N_ = in_sizes[0] / 128;
    const int E_ = in_sizes[1] / 2;
    const int* src = ei;
    const int* dst = ei + E_;

    float* out = (float*)d_out;
    size_t S = (size_t)N_ * 64;
    unsigned short* h0 = (unsigned short*)d_ws;          // S bf16
    unsigned short* f1 = h0 + S;                         // S bf16
    unsigned short* f2 = f1 + S;                         // S bf16
    int* rowptr = (int*)(f2 + S);                        // N+1
    int* col    = rowptr + (N_ + 1);                     // E

    const int NB    = (E_ + EPB - 1) / EPB;              // partition blocks (<=256)
    const int NBUCK = (N_ + 255) / 256;                  // dst buckets

    // aliases (consumed before f1 is first written by the hops)
    unsigned int* packed = (unsigned int*)f1;            // E uints
    int* table = (int*)(col + E_);                       // 256*NB
    int* exclT = table + 256 * NB;                       // 256*NB
    int* bsumT = exclT + 256 * NB;                       // 256
    int* bofsT = bsumT + 256;                            // 256
    unsigned short* w1b = (unsigned short*)(bofsT + 256); // 128*128 bf16
    unsigned short* w2b = w1b + 16384;                    // 64*64 bf16

    dim3 blk(256);
    int grid_g    = (N_ + 63) / 64;
    int node_grid = (N_ + 7) / 8;
    int nT        = 256 * NB;
    int nbT       = (nT + 255) / 256;                    // == NB

    // ---------------- CSR build (weight convert fused into part_hist) ------
    part_hist_kernel<<<NB, blk, 0, stream>>>(dst, table, E_, NB,
                                             W1, resW1, W2, w1b, w2b);
    scanA_kernel<<<nbT, blk, 0, stream>>>(table, exclT, bsumT, nT);
    scanB_kernel<<<1, blk, 0, stream>>>(bsumT, bofsT, nbT);
    part_scatter_kernel<<<NB, blk, 0, stream>>>(src, dst, exclT, bofsT, packed, E_, NB);
    bucket_build_kernel<<<NBUCK, blk, 0, stream>>>(packed, exclT, bofsT, rowptr, col,
                                                   E_, NB, N_);

    // ---------------- layer 1 ----------------
    gemm_l1_mfma<<<grid_g, blk, 0, stream>>>(x, w1b, h0, out, N_);
    hop_csr_kernel<<<node_grid, blk, 0, stream>>>(h0, f1, rowptr, col, N_);
    hop_csr_kernel<<<node_grid, blk, 0, stream>>>(f1, f2, rowptr, col, N_);
    hop3_combine_kernel<0><<<node_grid, blk, 0, stream>>>(h0, f1, f2, out, att1, bias1, out,
                                                          rowptr, col, N_);

    // ---------------- layer 2 ----------------
    gemm_l2_mfma<<<grid_g, blk, 0, stream>>>(out, w2b, h0, N_);
    hop_csr_kernel<<<node_grid, blk, 0, stream>>>(h0, f1, rowptr, col, N_);
    hop_csr_kernel<<<node_grid, blk, 0, stream>>>(f1, f2, rowptr, col, N_);
    hop3_combine_kernel<1><<<node_grid, blk, 0, stream>>>(h0, f1, f2, nullptr, att2, bias2, out,
                                                          rowptr, col, N_);
}

// Round 11
// 177.450 us; speedup vs baseline: 1.3994x; 1.0125x over previous
//
#include <hip/hip_runtime.h>
#include <math.h>

// ---------------------------------------------------------------------------
// AGDN via CSR-gather, bf16 propagated features.
//   GEMMs: bf16 MFMA (mfma_f32_16x16x32_bf16), fp32 accum.
//   CSR build: part_hist(+w convert) -> scanA -> part_scatter -> bucket_build
//     (bsum scan done redundantly in LDS by consumers; no scanB dispatch).
//   Hops/combines: TWO nodes per wave (32-lane half each), 4 edge-slots x
//     8 octets, 4-deep unrolled uint4 bf16 gather (4 loads in flight/lane).
// ---------------------------------------------------------------------------

#define EPB 4096     // edges per partition block
#define CAP 8192     // LDS col capacity per bucket (avg ~4096)

typedef __attribute__((ext_vector_type(8))) short bf16x8;
typedef __attribute__((ext_vector_type(4))) float f32x4;
typedef __attribute__((ext_vector_type(2))) float f32x2;

__device__ __forceinline__ unsigned short f2bf(float f)
{
    unsigned int t = __builtin_bit_cast(unsigned int, f);
    t += 0x7FFFu + ((t >> 16) & 1u);          // round-to-nearest-even
    return (unsigned short)(t >> 16);
}
__device__ __forceinline__ float bflo(unsigned int u)
{
    return __builtin_bit_cast(float, u << 16);
}
__device__ __forceinline__ float bfhi(unsigned int u)
{
    return __builtin_bit_cast(float, u & 0xFFFF0000u);
}
__device__ __forceinline__ f32x2 up2v(unsigned int u)
{
    f32x2 r;
    r.x = bflo(u);
    r.y = bfhi(u);
    return r;
}

// ---------------- layer-1 GEMM (MFMA): 64 nodes/block, 128 outputs ---------
// w1b rows 0..63 = W1 (-> h0 bf16), rows 64..127 = resW1 (-> res fp32)
#define LD1 136   // bf16 elems per LDS row (272 B stride: 4-bank shift/row)
__global__ __launch_bounds__(256)
void gemm_l1_mfma(const float* __restrict__ x,
                  const unsigned short* __restrict__ w1b,
                  unsigned short* __restrict__ h0, float* __restrict__ res, int n)
{
    __shared__ unsigned short xs[64 * LD1];
    __shared__ unsigned short ws[128 * LD1];
    const int tid = threadIdx.x;
    const int n0 = blockIdx.x * 64;

    for (int i = tid; i < 128 * 16; i += 256) {
        int r = i >> 4, c8 = (i & 15) * 8;
        *(uint4*)&ws[r * LD1 + c8] = *(const uint4*)&w1b[r * 128 + c8];
    }
    for (int i = tid; i < 64 * 32; i += 256) {
        int r = i >> 5, c4 = (i & 31) * 4;
        int nn = n0 + r;
        float4 v = (nn < n) ? *(const float4*)&x[(size_t)nn * 128 + c4]
                            : make_float4(0.f, 0.f, 0.f, 0.f);
        uint2 o;
        o.x = (unsigned)f2bf(v.x) | ((unsigned)f2bf(v.y) << 16);
        o.y = (unsigned)f2bf(v.z) | ((unsigned)f2bf(v.w) << 16);
        *(uint2*)&xs[r * LD1 + c4] = o;
    }
    __syncthreads();

    const int wv = tid >> 6, l = tid & 63;
    const int lrow = l & 15, lk = l >> 4;     // frag row / k-group
    f32x4 acc[8] = {};
    const unsigned short* ax = &xs[(wv * 16 + lrow) * LD1 + lk * 8];
    const unsigned short* bw = &ws[lrow * LD1 + lk * 8];

    #pragma unroll
    for (int s = 0; s < 4; ++s) {            // K = 128 = 4 x 32
        bf16x8 a = *(const bf16x8*)&ax[s * 32];
        #pragma unroll
        for (int t = 0; t < 8; ++t) {        // 8 output tiles of 16
            bf16x8 b = *(const bf16x8*)&bw[(size_t)t * 16 * LD1 + s * 32];
            acc[t] = __builtin_amdgcn_mfma_f32_16x16x32_bf16(a, b, acc[t], 0, 0, 0);
        }
    }

    #pragma unroll
    for (int t = 0; t < 8; ++t) {
        #pragma unroll
        for (int r = 0; r < 4; ++r) {        // D row = lk*4 + r, col = lrow
            int node = n0 + wv * 16 + lk * 4 + r;
            if (node < n) {
                if (t < 4) h0[(size_t)node * 64 + t * 16 + lrow] = f2bf(acc[t][r]);
                else       res[(size_t)node * 64 + (t - 4) * 16 + lrow] = acc[t][r];
            }
        }
    }
}

// ---------------- layer-2 GEMM (MFMA): 64 nodes/block, 64 outputs ----------
#define LD2 72    // 144 B stride
__global__ __launch_bounds__(256)
void gemm_l2_mfma(const float* __restrict__ h,
                  const unsigned short* __restrict__ w2b,
                  unsigned short* __restrict__ h0, int n)
{
    __shared__ unsigned short xs[64 * LD2];
    __shared__ unsigned short ws[64 * LD2];
    const int tid = threadIdx.x;
    const int n0 = blockIdx.x * 64;

    for (int i = tid; i < 64 * 8; i += 256) {
        int r = i >> 3, c8 = (i & 7) * 8;
        *(uint4*)&ws[r * LD2 + c8] = *(const uint4*)&w2b[r * 64 + c8];
    }
    for (int i = tid; i < 64 * 16; i += 256) {
        int r = i >> 4, c4 = (i & 15) * 4;
        int nn = n0 + r;
        float4 v = (nn < n) ? *(const float4*)&h[(size_t)nn * 64 + c4]
                            : make_float4(0.f, 0.f, 0.f, 0.f);
        uint2 o;
        o.x = (unsigned)f2bf(v.x) | ((unsigned)f2bf(v.y) << 16);
        o.y = (unsigned)f2bf(v.z) | ((unsigned)f2bf(v.w) << 16);
        *(uint2*)&xs[r * LD2 + c4] = o;
    }
    __syncthreads();

    const int wv = tid >> 6, l = tid & 63;
    const int lrow = l & 15, lk = l >> 4;
    f32x4 acc[4] = {};
    const unsigned short* ax = &xs[(wv * 16 + lrow) * LD2 + lk * 8];
    const unsigned short* bw = &ws[lrow * LD2 + lk * 8];

    #pragma unroll
    for (int s = 0; s < 2; ++s) {            // K = 64 = 2 x 32
        bf16x8 a = *(const bf16x8*)&ax[s * 32];
        #pragma unroll
        for (int t = 0; t < 4; ++t) {
            bf16x8 b = *(const bf16x8*)&bw[(size_t)t * 16 * LD2 + s * 32];
            acc[t] = __builtin_amdgcn_mfma_f32_16x16x32_bf16(a, b, acc[t], 0, 0, 0);
        }
    }

    #pragma unroll
    for (int t = 0; t < 4; ++t) {
        #pragma unroll
        for (int r = 0; r < 4; ++r) {
            int node = n0 + wv * 16 + lk * 4 + r;
            if (node < n)
                h0[(size_t)node * 64 + t * 16 + lrow] = f2bf(acc[t][r]);
        }
    }
}

// ---------------- CSR build ----------------
// coarse hist (+ fused weight conversion: NB*256 threads cover 20480 elems)
__global__ __launch_bounds__(256)
void part_hist_kernel(const int* __restrict__ dst, int* __restrict__ table,
                      int E, int NB,
                      const float* __restrict__ W1, const float* __restrict__ Wres,
                      const float* __restrict__ W2,
                      unsigned short* __restrict__ w1b, unsigned short* __restrict__ w2b)
{
    int gi = blockIdx.x * 256 + threadIdx.x;
    if (gi < 8192)       w1b[gi] = f2bf(W1[gi]);
    else if (gi < 16384) w1b[gi] = f2bf(Wres[gi - 8192]);
    else if (gi < 20480) w2b[gi - 16384] = f2bf(W2[gi - 16384]);

    __shared__ int h[256];
    h[threadIdx.x] = 0;
    __syncthreads();
    int base = blockIdx.x * EPB;
    for (int i = threadIdx.x; i < EPB; i += 256) {
        int e = base + i;
        if (e < E) atomicAdd(&h[((unsigned)dst[e]) >> 8], 1);
    }
    __syncthreads();
    table[threadIdx.x * NB + blockIdx.x] = h[threadIdx.x];   // bin-major
}

__global__ __launch_bounds__(256)
void scanA_kernel(const int* __restrict__ cnt, int* __restrict__ excl,
                  int* __restrict__ bsum, int n)
{
    __shared__ int sh[256];
    int i = blockIdx.x * 256 + threadIdx.x;
    int v = (i < n) ? cnt[i] : 0;
    sh[threadIdx.x] = v;
    __syncthreads();
    #pragma unroll
    for (int off = 1; off < 256; off <<= 1) {
        int t = (threadIdx.x >= off) ? sh[threadIdx.x - off] : 0;
        __syncthreads();
        sh[threadIdx.x] += t;
        __syncthreads();
    }
    if (i < n) excl[i] = sh[threadIdx.x] - v;
    if (threadIdx.x == 255) bsum[blockIdx.x] = sh[255];
}

// per-block LDS reorder -> packed (dst<<16 | src); bsum scan done locally
__global__ __launch_bounds__(256)
void part_scatter_kernel(const int* __restrict__ src, const int* __restrict__ dst,
                         const int* __restrict__ exclT, const int* __restrict__ bsumT,
                         unsigned int* __restrict__ packed, int E, int NB, int nbT)
{
    __shared__ int lhist[256];
    __shared__ int sh[256];
    __shared__ int lexcl[256];
    __shared__ int lcur[256];
    __shared__ int gb2[256];
    __shared__ int bofsL[256];
    __shared__ unsigned int lp[EPB];
    __shared__ unsigned char lbin[EPB];

    const int tid = threadIdx.x;
    const int base = blockIdx.x * EPB;
    const int cntE = min(EPB, E - base);

    unsigned int pv[16];
    int pb[16];
    lhist[tid] = 0;
    __syncthreads();
    #pragma unroll
    for (int it = 0; it < 16; ++it) {
        int i = it * 256 + tid;
        pv[it] = 0; pb[it] = -1;
        if (i < cntE) {
            int e = base + i;
            unsigned int p = (((unsigned)dst[e]) << 16) | (unsigned)src[e];
            pv[it] = p;
            pb[it] = (int)(p >> 24);
            atomicAdd(&lhist[pb[it]], 1);
        }
    }
    __syncthreads();
    // scan of lhist
    sh[tid] = lhist[tid];
    __syncthreads();
    #pragma unroll
    for (int off = 1; off < 256; off <<= 1) {
        int t = (tid >= off) ? sh[tid - off] : 0;
        __syncthreads();
        sh[tid] += t;
        __syncthreads();
    }
    lexcl[tid] = sh[tid] - lhist[tid];
    lcur[tid] = sh[tid] - lhist[tid];
    __syncthreads();
    // local scan of bsumT (replaces scanB dispatch)
    int bv = (tid < nbT) ? bsumT[tid] : 0;
    sh[tid] = bv;
    __syncthreads();
    #pragma unroll
    for (int off = 1; off < 256; off <<= 1) {
        int t = (tid >= off) ? sh[tid - off] : 0;
        __syncthreads();
        sh[tid] += t;
        __syncthreads();
    }
    bofsL[tid] = sh[tid] - bv;
    __syncthreads();
    int ti = tid * NB + blockIdx.x;
    gb2[tid] = exclT[ti] + bofsL[ti >> 8] - lexcl[tid];
    __syncthreads();
    #pragma unroll
    for (int it = 0; it < 16; ++it) {
        if (pb[it] >= 0) {
            int slot = atomicAdd(&lcur[pb[it]], 1);
            lp[slot] = pv[it];
            lbin[slot] = (unsigned char)pb[it];
        }
    }
    __syncthreads();
    for (int i = tid; i < cntE; i += 256)
        packed[gb2[lbin[i]] + i] = lp[i];
}

// fused fine stage, single global pass: stage packed run in LDS, then
// hist + scan + rowptr + scatter + coalesced col copy-out. bsum scan local.
__global__ __launch_bounds__(256)
void bucket_build_kernel(const unsigned int* __restrict__ packed,
                         const int* __restrict__ exclT, const int* __restrict__ bsumT,
                         int* __restrict__ rowptr, int* __restrict__ col,
                         int E, int NB, int N, int nbT)
{
    __shared__ int h[256];
    __shared__ int sh[256];
    __shared__ int lcur[256];
    __shared__ int bofsL[256];
    __shared__ unsigned int lp[CAP];
    __shared__ unsigned short colS[CAP];

    const int b = blockIdx.x;
    const int t = threadIdx.x;

    // local scan of bsumT
    int bv = (t < nbT) ? bsumT[t] : 0;
    sh[t] = bv;
    __syncthreads();
    #pragma unroll
    for (int off = 1; off < 256; off <<= 1) {
        int v = (t >= off) ? sh[t - off] : 0;
        __syncthreads();
        sh[t] += v;
        __syncthreads();
    }
    bofsL[t] = sh[t] - bv;
    __syncthreads();

    int i0 = exclT[b * NB] + bofsL[(b * NB) >> 8];
    int bn = (b + 1) * NB;
    int i1 = (b == gridDim.x - 1) ? E : (exclT[bn] + bofsL[bn >> 8]);
    int cB = i1 - i0;

    h[t] = 0;
    __syncthreads();
    for (int i = t; i < cB; i += 256) {
        unsigned int p = packed[i0 + i];
        if (i < CAP) lp[i] = p;
        atomicAdd(&h[(p >> 16) & 255], 1);
    }
    __syncthreads();
    sh[t] = h[t];
    __syncthreads();
    #pragma unroll
    for (int off = 1; off < 256; off <<= 1) {
        int v = (t >= off) ? sh[t - off] : 0;
        __syncthreads();
        sh[t] += v;
        __syncthreads();
    }
    int excl = sh[t] - h[t];
    int d = b * 256 + t;
    if (d < N) rowptr[d] = i0 + excl;            // coalesced rowptr write
    if (b == gridDim.x - 1 && t == 0) rowptr[N] = E;
    lcur[t] = excl;
    __syncthreads();
    for (int i = t; i < cB; i += 256) {
        unsigned int p = (i < CAP) ? lp[i] : packed[i0 + i];
        int lo = (p >> 16) & 255;
        int r = atomicAdd(&lcur[lo], 1);
        if (r < CAP) colS[r] = (unsigned short)(p & 0xFFFFu);
        else col[i0 + r] = (int)(p & 0xFFFFu);
    }
    __syncthreads();
    for (int i = t; i < cB && i < CAP; i += 256)
        col[i0 + i] = (int)colS[i];
}

// ---------------- hop: TWO nodes/wave; 4 slots x 8 octets; 4-deep unroll ---
__global__ __launch_bounds__(256)
void hop_csr_kernel(const unsigned short* __restrict__ fin,
                    unsigned short* __restrict__ fout,
                    const int* __restrict__ rowptr, const int* __restrict__ col, int n)
{
    int lane = threadIdx.x & 63;
    int node = blockIdx.x * 8 + ((threadIdx.x >> 6) << 1) + (lane >> 5);
    if (node >= n) return;
    int sub = (lane >> 3) & 3;      // edge slot 0..3
    int fo = (lane & 7) * 8;        // feature octet start

    int beg = rowptr[node], end = rowptr[node + 1];
    f32x2 ac[4] = {};
    for (int b = beg + sub; b < end; b += 16) {
        int e1 = b + 4, e2 = b + 8, e3 = b + 12;
        uint4 u0 = *(const uint4*)&fin[(size_t)col[b] * 64 + fo];
        uint4 u1 = make_uint4(0, 0, 0, 0);
        uint4 u2 = make_uint4(0, 0, 0, 0);
        uint4 u3 = make_uint4(0, 0, 0, 0);
        if (e1 < end) u1 = *(const uint4*)&fin[(size_t)col[e1] * 64 + fo];
        if (e2 < end) u2 = *(const uint4*)&fin[(size_t)col[e2] * 64 + fo];
        if (e3 < end) u3 = *(const uint4*)&fin[(size_t)col[e3] * 64 + fo];
        ac[0] += up2v(u0.x); ac[1] += up2v(u0.y);
        ac[2] += up2v(u0.z); ac[3] += up2v(u0.w);
        ac[0] += up2v(u1.x); ac[1] += up2v(u1.y);
        ac[2] += up2v(u1.z); ac[3] += up2v(u1.w);
        ac[0] += up2v(u2.x); ac[1] += up2v(u2.y);
        ac[2] += up2v(u2.z); ac[3] += up2v(u2.w);
        ac[0] += up2v(u3.x); ac[1] += up2v(u3.y);
        ac[2] += up2v(u3.z); ac[3] += up2v(u3.w);
    }
    float a[8] = {ac[0].x, ac[0].y, ac[1].x, ac[1].y,
                  ac[2].x, ac[2].y, ac[3].x, ac[3].y};
    #pragma unroll
    for (int off = 8; off <= 16; off <<= 1)        // reduce over 4 sub-slots
        #pragma unroll
        for (int k = 0; k < 8; ++k)
            a[k] += __shfl_xor(a[k], off);
    if (sub == 0) {
        uint4 o;
        o.x = (unsigned)f2bf(a[0]) | ((unsigned)f2bf(a[1]) << 16);
        o.y = (unsigned)f2bf(a[2]) | ((unsigned)f2bf(a[3]) << 16);
        o.z = (unsigned)f2bf(a[4]) | ((unsigned)f2bf(a[5]) << 16);
        o.w = (unsigned)f2bf(a[6]) | ((unsigned)f2bf(a[7]) << 16);
        *(uint4*)&fout[(size_t)node * 64 + fo] = o;
    }
}

// ---------------- 3rd hop fused with attention combine (2 nodes/wave) ------
// MODE 0: layer 1 (res from fp32 res buffer, apply ELU); MODE 1: layer 2.
template<int MODE>
__global__ __launch_bounds__(256)
void hop3_combine_kernel(const unsigned short* __restrict__ h0,
                         const unsigned short* __restrict__ f1,
                         const unsigned short* __restrict__ f2,
                         const float* __restrict__ res, const float* __restrict__ att,
                         const float* __restrict__ bias, float* __restrict__ out,
                         const int* __restrict__ rowptr, const int* __restrict__ col, int n)
{
    int lane = threadIdx.x & 63;
    int node = blockIdx.x * 8 + ((threadIdx.x >> 6) << 1) + (lane >> 5);
    if (node >= n) return;
    int sub = (lane >> 3) & 3;      // edge slot 0..3
    int fo = (lane & 7) * 8;        // feature octet start
    size_t rbase = (size_t)node * 64 + fo;

    // f3 octet = gather-sum of f2 rows (4-deep unrolled)
    int beg = rowptr[node], end = rowptr[node + 1];
    f32x2 ac[4] = {};
    for (int b = beg + sub; b < end; b += 16) {
        int e1 = b + 4, e2 = b + 8, e3 = b + 12;
        uint4 u0 = *(const uint4*)&f2[(size_t)col[b] * 64 + fo];
        uint4 u1 = make_uint4(0, 0, 0, 0);
        uint4 u2 = make_uint4(0, 0, 0, 0);
        uint4 u3 = make_uint4(0, 0, 0, 0);
        if (e1 < end) u1 = *(const uint4*)&f2[(size_t)col[e1] * 64 + fo];
        if (e2 < end) u2 = *(const uint4*)&f2[(size_t)col[e2] * 64 + fo];
        if (e3 < end) u3 = *(const uint4*)&f2[(size_t)col[e3] * 64 + fo];
        ac[0] += up2v(u0.x); ac[1] += up2v(u0.y);
        ac[2] += up2v(u0.z); ac[3] += up2v(u0.w);
        ac[0] += up2v(u1.x); ac[1] += up2v(u1.y);
        ac[2] += up2v(u1.z); ac[3] += up2v(u1.w);
        ac[0] += up2v(u2.x); ac[1] += up2v(u2.y);
        ac[2] += up2v(u2.z); ac[3] += up2v(u2.w);
        ac[0] += up2v(u3.x); ac[1] += up2v(u3.y);
        ac[2] += up2v(u3.z); ac[3] += up2v(u3.w);
    }
    float a[8] = {ac[0].x, ac[0].y, ac[1].x, ac[1].y,
                  ac[2].x, ac[2].y, ac[3].x, ac[3].y};
    #pragma unroll
    for (int off = 8; off <= 16; off <<= 1)        // reduce over 4 sub-slots
        #pragma unroll
        for (int k = 0; k < 8; ++k)
            a[k] += __shfl_xor(a[k], off);
    // every lane of the 32-lane half now holds the full f3 octet for fo..fo+7

    uint4 r0 = *(const uint4*)&h0[rbase];
    uint4 r1 = *(const uint4*)&f1[rbase];
    uint4 r2 = *(const uint4*)&f2[rbase];
    float v0f[8] = {bflo(r0.x), bfhi(r0.x), bflo(r0.y), bfhi(r0.y),
                    bflo(r0.z), bfhi(r0.z), bflo(r0.w), bfhi(r0.w)};
    float v1f[8] = {bflo(r1.x), bfhi(r1.x), bflo(r1.y), bfhi(r1.y),
                    bflo(r1.z), bfhi(r1.z), bflo(r1.w), bfhi(r1.w)};
    float v2f[8] = {bflo(r2.x), bfhi(r2.x), bflo(r2.y), bfhi(r2.y),
                    bflo(r2.z), bfhi(r2.z), bflo(r2.w), bfhi(r2.w)};

    float4 alo0 = *(const float4*)&att[fo];
    float4 alo1 = *(const float4*)&att[fo + 4];
    float4 ahi0 = *(const float4*)&att[64 + fo];
    float4 ahi1 = *(const float4*)&att[64 + fo + 4];
    float alo[8] = {alo0.x, alo0.y, alo0.z, alo0.w, alo1.x, alo1.y, alo1.z, alo1.w};
    float ahi[8] = {ahi0.x, ahi0.y, ahi0.z, ahi0.w, ahi1.x, ahi1.y, ahi1.z, ahi1.w};

    // per-octet partial dot products, then 3-level reduce over octets
    float p0 = 0.f, q0 = 0.f, q1 = 0.f, q2 = 0.f, q3 = 0.f;
    #pragma unroll
    for (int j = 0; j < 8; ++j) {
        p0 += v0f[j] * alo[j];
        q0 += v0f[j] * ahi[j];
        q1 += v1f[j] * ahi[j];
        q2 += v2f[j] * ahi[j];
        q3 += a[j]   * ahi[j];
    }
    #pragma unroll
    for (int off = 1; off <= 4; off <<= 1) {
        p0 += __shfl_xor(p0, off);
        q0 += __shfl_xor(q0, off);
        q1 += __shfl_xor(q1, off);
        q2 += __shfl_xor(q2, off);
        q3 += __shfl_xor(q3, off);
    }

    float s0 = p0 + q0, s1 = p0 + q1, s2 = p0 + q2, s3 = p0 + q3;
    s0 = s0 > 0.f ? s0 : 0.2f * s0;
    s1 = s1 > 0.f ? s1 : 0.2f * s1;
    s2 = s2 > 0.f ? s2 : 0.2f * s2;
    s3 = s3 > 0.f ? s3 : 0.2f * s3;
    float m = fmaxf(fmaxf(s0, s1), fmaxf(s2, s3));
    float E0 = __expf(s0 - m), E1 = __expf(s1 - m);
    float E2 = __expf(s2 - m), E3 = __expf(s3 - m);
    float inv = 1.f / (E0 + E1 + E2 + E3);
    float w0 = E0 * inv, w1 = E1 * inv, w2 = E2 * inv, w3 = E3 * inv;

    float rsv[8];
    if (MODE == 0) {
        float4 ra = *(const float4*)&res[rbase];
        float4 rb = *(const float4*)&res[rbase + 4];
        rsv[0] = ra.x; rsv[1] = ra.y; rsv[2] = ra.z; rsv[3] = ra.w;
        rsv[4] = rb.x; rsv[5] = rb.y; rsv[6] = rb.z; rsv[7] = rb.w;
    } else {
        #pragma unroll
        for (int j = 0; j < 8; ++j) rsv[j] = v0f[j];
    }
    float4 ba = *(const float4*)&bias[fo];
    float4 bb = *(const float4*)&bias[fo + 4];
    float bi[8] = {ba.x, ba.y, ba.z, ba.w, bb.x, bb.y, bb.z, bb.w};

    float o[8];
    #pragma unroll
    for (int j = 0; j < 8; ++j) {
        float v = w0 * v0f[j] + w1 * v1f[j] + w2 * v2f[j] + w3 * a[j];
        v += rsv[j] + bi[j];
        if (MODE == 0) v = v > 0.f ? v : __expf(v) - 1.f;   // ELU(alpha=1)
        o[j] = v;
    }
    if (sub == 0) {
        *(float4*)&out[rbase]     = make_float4(o[0], o[1], o[2], o[3]);
        *(float4*)&out[rbase + 4] = make_float4(o[4], o[5], o[6], o[7]);
    }
}

extern "C" void kernel_launch(void* const* d_in, const int* in_sizes, int n_in,
                              void* d_out, int out_size, void* d_ws, size_t ws_size,
                              hipStream_t stream)
{
    const float* x     = (const float*)d_in[0];
    const int*   ei    = (const int*)  d_in[1];
    const float* W1    = (const float*)d_in[2];
    const float* att1  = (const float*)d_in[3];
    const float* bias1 = (const float*)d_in[4];
    const float* resW1 = (const float*)d_in[5];
    const float* W2    = (const float*)d_in[6];
    const float* att2  = (const float*)d_in[7];
    const float* bias2 = (const float*)d_in[8];

    const int N_ = in_sizes[0] / 128;
    const int E_ = in_sizes[1] / 2;
    const int* src = ei;
    const int* dst = ei + E_;

    float* out = (float*)d_out;
    size_t S = (size_t)N_ * 64;
    unsigned short* h0 = (unsigned short*)d_ws;          // S bf16
    unsigned short* f1 = h0 + S;                         // S bf16
    unsigned short* f2 = f1 + S;                         // S bf16
    int* rowptr = (int*)(f2 + S);                        // N+1
    int* col    = rowptr + (N_ + 1);                     // E

    const int NB    = (E_ + EPB - 1) / EPB;              // partition blocks (<=256)
    const int NBUCK = (N_ + 255) / 256;                  // dst buckets

    // aliases (consumed before f1 is first written by the hops)
    unsigned int* packed = (unsigned int*)f1;            // E uints
    int* table = (int*)(col + E_);                       // 256*NB
    int* exclT = table + 256 * NB;                       // 256*NB
    int* bsumT = exclT + 256 * NB;                       // 256
    unsigned short* w1b = (unsigned short*)(bsumT + 256); // 128*128 bf16
    unsigned short* w2b = w1b + 16384;                    // 64*64 bf16

    dim3 blk(256);
    int grid_g    = (N_ + 63) / 64;
    int node_grid = (N_ + 7) / 8;
    int nT        = 256 * NB;
    int nbT       = (nT + 255) / 256;                    // == NB

    // ---------------- CSR build (weight convert fused into part_hist) ------
    part_hist_kernel<<<NB, blk, 0, stream>>>(dst, table, E_, NB,
                                             W1, resW1, W2, w1b, w2b);
    scanA_kernel<<<nbT, blk, 0, stream>>>(table, exclT, bsumT, nT);
    part_scatter_kernel<<<NB, blk, 0, stream>>>(src, dst, exclT, bsumT, packed,
                                                E_, NB, nbT);
    bucket_build_kernel<<<NBUCK, blk, 0, stream>>>(packed, exclT, bsumT, rowptr, col,
                                                   E_, NB, N_, nbT);

    // ---------------- layer 1 ----------------
    gemm_l1_mfma<<<grid_g, blk, 0, stream>>>(x, w1b, h0, out, N_);
    hop_csr_kernel<<<node_grid, blk, 0, stream>>>(h0, f1, rowptr, col, N_);
    hop_csr_kernel<<<node_grid, blk, 0, stream>>>(f1, f2, rowptr, col, N_);
    hop3_combine_kernel<0><<<node_grid, blk, 0, stream>>>(h0, f1, f2, out, att1, bias1, out,
                                                          rowptr, col, N_);

    // ---------------- layer 2 ----------------
    gemm_l2_mfma<<<grid_g, blk, 0, stream>>>(out, w2b, h0, N_);
    hop_csr_kernel<<<node_grid, blk, 0, stream>>>(h0, f1, rowptr, col, N_);
    hop_csr_kernel<<<node_grid, blk, 0, stream>>>(f1, f2, rowptr, col, N_);
    hop3_combine_kernel<1><<<node_grid, blk, 0, stream>>>(h0, f1, f2, nullptr, att2, bias2, out,
                                                          rowptr, col, N_);
}

// Round 12
// 173.112 us; speedup vs baseline: 1.4345x; 1.0251x over previous
//
#include <hip/hip_runtime.h>
#include <math.h>

// ---------------------------------------------------------------------------
// AGDN via CSR-gather, bf16 propagated features.
//   Dispatch 1 fuses: layer-1 MFMA GEMM (inline fp32->bf16 W staging) +
//     coarse dst-histogram + W2 bf16 conversion (independent work, one grid).
//   CSR build: scanA -> part_scatter (bin recomputed from packed>>24) ->
//     bucket_build (single global pass, LDS-staged).
//   Hops/combines: TWO nodes per wave (32-lane half each), 4 edge-slots x
//     8 octets, 4-deep unrolled uint4 bf16 gather. Transaction-bound floor.
// ---------------------------------------------------------------------------

#define EPB 4096     // edges per partition block
#define CAP 8192     // LDS col capacity per bucket (avg ~4096)

typedef __attribute__((ext_vector_type(8))) short bf16x8;
typedef __attribute__((ext_vector_type(4))) float f32x4;
typedef __attribute__((ext_vector_type(2))) float f32x2;

__device__ __forceinline__ unsigned short f2bf(float f)
{
    unsigned int t = __builtin_bit_cast(unsigned int, f);
    t += 0x7FFFu + ((t >> 16) & 1u);          // round-to-nearest-even
    return (unsigned short)(t >> 16);
}
__device__ __forceinline__ float bflo(unsigned int u)
{
    return __builtin_bit_cast(float, u << 16);
}
__device__ __forceinline__ float bfhi(unsigned int u)
{
    return __builtin_bit_cast(float, u & 0xFFFF0000u);
}
__device__ __forceinline__ f32x2 up2v(unsigned int u)
{
    f32x2 r;
    r.x = bflo(u);
    r.y = bfhi(u);
    return r;
}

// ---------------- dispatch 1: layer-1 GEMM + coarse hist + W2 convert ------
// blocks [0, NB):        coarse dst histogram (+ W2 fp32->bf16, 4096 elems)
// blocks [NB, NB+grid_g): 64-node MFMA GEMM, W1/resW1 converted inline
#define LD1 136   // bf16 elems per LDS row (272 B stride: 4-bank shift/row)
__global__ __launch_bounds__(256)
void gemm_l1_hist_kernel(const float* __restrict__ x,
                         const float* __restrict__ W1, const float* __restrict__ Wres,
                         unsigned short* __restrict__ h0, float* __restrict__ res, int n,
                         const int* __restrict__ dst, int* __restrict__ table,
                         int E, int NB,
                         const float* __restrict__ W2, unsigned short* __restrict__ w2b)
{
    __shared__ unsigned short xs[64 * LD1];
    __shared__ unsigned short ws[128 * LD1];
    const int tid = threadIdx.x;

    if ((int)blockIdx.x < NB) {               // ---- histogram role ----
        int hb = blockIdx.x;
        int gi = hb * 256 + tid;
        if (gi < 4096) w2b[gi] = f2bf(W2[gi]);

        int* h = (int*)xs;                    // reuse LDS
        h[tid] = 0;
        __syncthreads();
        int base = hb * EPB;
        for (int i = tid; i < EPB; i += 256) {
            int e = base + i;
            if (e < E) atomicAdd(&h[((unsigned)dst[e]) >> 8], 1);
        }
        __syncthreads();
        table[tid * NB + hb] = h[tid];        // bin-major
        return;
    }

    // ---- GEMM role ----
    const int n0 = ((int)blockIdx.x - NB) * 64;

    // stage W1 (rows 0..63) + resW1 (rows 64..127), fp32 -> bf16 inline
    for (int i = tid; i < 128 * 32; i += 256) {
        int r = i >> 5, c4 = (i & 31) * 4;
        const float* wsrc = (r < 64) ? &W1[(size_t)r * 128 + c4]
                                     : &Wres[(size_t)(r - 64) * 128 + c4];
        float4 v = *(const float4*)wsrc;
        uint2 o;
        o.x = (unsigned)f2bf(v.x) | ((unsigned)f2bf(v.y) << 16);
        o.y = (unsigned)f2bf(v.z) | ((unsigned)f2bf(v.w) << 16);
        *(uint2*)&ws[r * LD1 + c4] = o;
    }
    for (int i = tid; i < 64 * 32; i += 256) {
        int r = i >> 5, c4 = (i & 31) * 4;
        int nn = n0 + r;
        float4 v = (nn < n) ? *(const float4*)&x[(size_t)nn * 128 + c4]
                            : make_float4(0.f, 0.f, 0.f, 0.f);
        uint2 o;
        o.x = (unsigned)f2bf(v.x) | ((unsigned)f2bf(v.y) << 16);
        o.y = (unsigned)f2bf(v.z) | ((unsigned)f2bf(v.w) << 16);
        *(uint2*)&xs[r * LD1 + c4] = o;
    }
    __syncthreads();

    const int wv = tid >> 6, l = tid & 63;
    const int lrow = l & 15, lk = l >> 4;     // frag row / k-group
    f32x4 acc[8] = {};
    const unsigned short* ax = &xs[(wv * 16 + lrow) * LD1 + lk * 8];
    const unsigned short* bw = &ws[lrow * LD1 + lk * 8];

    #pragma unroll
    for (int s = 0; s < 4; ++s) {            // K = 128 = 4 x 32
        bf16x8 a = *(const bf16x8*)&ax[s * 32];
        #pragma unroll
        for (int t = 0; t < 8; ++t) {        // 8 output tiles of 16
            bf16x8 b = *(const bf16x8*)&bw[(size_t)t * 16 * LD1 + s * 32];
            acc[t] = __builtin_amdgcn_mfma_f32_16x16x32_bf16(a, b, acc[t], 0, 0, 0);
        }
    }

    #pragma unroll
    for (int t = 0; t < 8; ++t) {
        #pragma unroll
        for (int r = 0; r < 4; ++r) {        // D row = lk*4 + r, col = lrow
            int node = n0 + wv * 16 + lk * 4 + r;
            if (node < n) {
                if (t < 4) h0[(size_t)node * 64 + t * 16 + lrow] = f2bf(acc[t][r]);
                else       res[(size_t)node * 64 + (t - 4) * 16 + lrow] = acc[t][r];
            }
        }
    }
}

// ---------------- layer-2 GEMM (MFMA): 64 nodes/block, 64 outputs ----------
#define LD2 72    // 144 B stride
__global__ __launch_bounds__(256)
void gemm_l2_mfma(const float* __restrict__ h,
                  const unsigned short* __restrict__ w2b,
                  unsigned short* __restrict__ h0, int n)
{
    __shared__ unsigned short xs[64 * LD2];
    __shared__ unsigned short ws[64 * LD2];
    const int tid = threadIdx.x;
    const int n0 = blockIdx.x * 64;

    for (int i = tid; i < 64 * 8; i += 256) {
        int r = i >> 3, c8 = (i & 7) * 8;
        *(uint4*)&ws[r * LD2 + c8] = *(const uint4*)&w2b[r * 64 + c8];
    }
    for (int i = tid; i < 64 * 16; i += 256) {
        int r = i >> 4, c4 = (i & 15) * 4;
        int nn = n0 + r;
        float4 v = (nn < n) ? *(const float4*)&h[(size_t)nn * 64 + c4]
                            : make_float4(0.f, 0.f, 0.f, 0.f);
        uint2 o;
        o.x = (unsigned)f2bf(v.x) | ((unsigned)f2bf(v.y) << 16);
        o.y = (unsigned)f2bf(v.z) | ((unsigned)f2bf(v.w) << 16);
        *(uint2*)&xs[r * LD2 + c4] = o;
    }
    __syncthreads();

    const int wv = tid >> 6, l = tid & 63;
    const int lrow = l & 15, lk = l >> 4;
    f32x4 acc[4] = {};
    const unsigned short* ax = &xs[(wv * 16 + lrow) * LD2 + lk * 8];
    const unsigned short* bw = &ws[lrow * LD2 + lk * 8];

    #pragma unroll
    for (int s = 0; s < 2; ++s) {            // K = 64 = 2 x 32
        bf16x8 a = *(const bf16x8*)&ax[s * 32];
        #pragma unroll
        for (int t = 0; t < 4; ++t) {
            bf16x8 b = *(const bf16x8*)&bw[(size_t)t * 16 * LD2 + s * 32];
            acc[t] = __builtin_amdgcn_mfma_f32_16x16x32_bf16(a, b, acc[t], 0, 0, 0);
        }
    }

    #pragma unroll
    for (int t = 0; t < 4; ++t) {
        #pragma unroll
        for (int r = 0; r < 4; ++r) {
            int node = n0 + wv * 16 + lk * 4 + r;
            if (node < n)
                h0[(size_t)node * 64 + t * 16 + lrow] = f2bf(acc[t][r]);
        }
    }
}

// ---------------- CSR build ----------------
__global__ __launch_bounds__(256)
void scanA_kernel(const int* __restrict__ cnt, int* __restrict__ excl,
                  int* __restrict__ bsum, int n)
{
    __shared__ int sh[256];
    int i = blockIdx.x * 256 + threadIdx.x;
    int v = (i < n) ? cnt[i] : 0;
    sh[threadIdx.x] = v;
    __syncthreads();
    #pragma unroll
    for (int off = 1; off < 256; off <<= 1) {
        int t = (threadIdx.x >= off) ? sh[threadIdx.x - off] : 0;
        __syncthreads();
        sh[threadIdx.x] += t;
        __syncthreads();
    }
    if (i < n) excl[i] = sh[threadIdx.x] - v;
    if (threadIdx.x == 255) bsum[blockIdx.x] = sh[255];
}

// per-block LDS reorder -> packed (dst<<16 | src); bsum scan done locally;
// bin recomputed from p>>24 at write time (no lbin array).
__global__ __launch_bounds__(256)
void part_scatter_kernel(const int* __restrict__ src, const int* __restrict__ dst,
                         const int* __restrict__ exclT, const int* __restrict__ bsumT,
                         unsigned int* __restrict__ packed, int E, int NB, int nbT)
{
    __shared__ int lhist[256];
    __shared__ int sh[256];
    __shared__ int lexcl[256];
    __shared__ int lcur[256];
    __shared__ int gb2[256];
    __shared__ int bofsL[256];
    __shared__ unsigned int lp[EPB];

    const int tid = threadIdx.x;
    const int base = blockIdx.x * EPB;
    const int cntE = min(EPB, E - base);

    unsigned int pv[16];
    int pb[16];
    lhist[tid] = 0;
    __syncthreads();
    #pragma unroll
    for (int it = 0; it < 16; ++it) {
        int i = it * 256 + tid;
        pv[it] = 0; pb[it] = -1;
        if (i < cntE) {
            int e = base + i;
            unsigned int p = (((unsigned)dst[e]) << 16) | (unsigned)src[e];
            pv[it] = p;
            pb[it] = (int)(p >> 24);
            atomicAdd(&lhist[pb[it]], 1);
        }
    }
    __syncthreads();
    // scan of lhist
    sh[tid] = lhist[tid];
    __syncthreads();
    #pragma unroll
    for (int off = 1; off < 256; off <<= 1) {
        int t = (tid >= off) ? sh[tid - off] : 0;
        __syncthreads();
        sh[tid] += t;
        __syncthreads();
    }
    lexcl[tid] = sh[tid] - lhist[tid];
    lcur[tid] = sh[tid] - lhist[tid];
    __syncthreads();
    // local scan of bsumT (replaces scanB dispatch)
    int bv = (tid < nbT) ? bsumT[tid] : 0;
    sh[tid] = bv;
    __syncthreads();
    #pragma unroll
    for (int off = 1; off < 256; off <<= 1) {
        int t = (tid >= off) ? sh[tid - off] : 0;
        __syncthreads();
        sh[tid] += t;
        __syncthreads();
    }
    bofsL[tid] = sh[tid] - bv;
    __syncthreads();
    int ti = tid * NB + blockIdx.x;
    gb2[tid] = exclT[ti] + bofsL[ti >> 8] - lexcl[tid];
    __syncthreads();
    #pragma unroll
    for (int it = 0; it < 16; ++it) {
        if (pb[it] >= 0) {
            int slot = atomicAdd(&lcur[pb[it]], 1);
            lp[slot] = pv[it];
        }
    }
    __syncthreads();
    for (int i = tid; i < cntE; i += 256) {
        unsigned int p = lp[i];
        packed[gb2[p >> 24] + i] = p;         // p>>24 == dst>>8 == bin
    }
}

// fused fine stage, single global pass: stage packed run in LDS, then
// hist + scan + rowptr + scatter + coalesced col copy-out. bsum scan local.
__global__ __launch_bounds__(256)
void bucket_build_kernel(const unsigned int* __restrict__ packed,
                         const int* __restrict__ exclT, const int* __restrict__ bsumT,
                         int* __restrict__ rowptr, int* __restrict__ col,
                         int E, int NB, int N, int nbT)
{
    __shared__ int h[256];
    __shared__ int sh[256];
    __shared__ int lcur[256];
    __shared__ int bofsL[256];
    __shared__ unsigned int lp[CAP];
    __shared__ unsigned short colS[CAP];

    const int b = blockIdx.x;
    const int t = threadIdx.x;

    // local scan of bsumT
    int bv = (t < nbT) ? bsumT[t] : 0;
    sh[t] = bv;
    __syncthreads();
    #pragma unroll
    for (int off = 1; off < 256; off <<= 1) {
        int v = (t >= off) ? sh[t - off] : 0;
        __syncthreads();
        sh[t] += v;
        __syncthreads();
    }
    bofsL[t] = sh[t] - bv;
    __syncthreads();

    int i0 = exclT[b * NB] + bofsL[(b * NB) >> 8];
    int bn = (b + 1) * NB;
    int i1 = (b == gridDim.x - 1) ? E : (exclT[bn] + bofsL[bn >> 8]);
    int cB = i1 - i0;

    h[t] = 0;
    __syncthreads();
    for (int i = t; i < cB; i += 256) {
        unsigned int p = packed[i0 + i];
        if (i < CAP) lp[i] = p;
        atomicAdd(&h[(p >> 16) & 255], 1);
    }
    __syncthreads();
    sh[t] = h[t];
    __syncthreads();
    #pragma unroll
    for (int off = 1; off < 256; off <<= 1) {
        int v = (t >= off) ? sh[t - off] : 0;
        __syncthreads();
        sh[t] += v;
        __syncthreads();
    }
    int excl = sh[t] - h[t];
    int d = b * 256 + t;
    if (d < N) rowptr[d] = i0 + excl;            // coalesced rowptr write
    if (b == gridDim.x - 1 && t == 0) rowptr[N] = E;
    lcur[t] = excl;
    __syncthreads();
    for (int i = t; i < cB; i += 256) {
        unsigned int p = (i < CAP) ? lp[i] : packed[i0 + i];
        int lo = (p >> 16) & 255;
        int r = atomicAdd(&lcur[lo], 1);
        if (r < CAP) colS[r] = (unsigned short)(p & 0xFFFFu);
        else col[i0 + r] = (int)(p & 0xFFFFu);
    }
    __syncthreads();
    for (int i = t; i < cB && i < CAP; i += 256)
        col[i0 + i] = (int)colS[i];
}

// ---------------- hop: TWO nodes/wave; 4 slots x 8 octets; 4-deep unroll ---
__global__ __launch_bounds__(256)
void hop_csr_kernel(const unsigned short* __restrict__ fin,
                    unsigned short* __restrict__ fout,
                    const int* __restrict__ rowptr, const int* __restrict__ col, int n)
{
    int lane = threadIdx.x & 63;
    int node = blockIdx.x * 8 + ((threadIdx.x >> 6) << 1) + (lane >> 5);
    if (node >= n) return;
    int sub = (lane >> 3) & 3;      // edge slot 0..3
    int fo = (lane & 7) * 8;        // feature octet start

    int beg = rowptr[node], end = rowptr[node + 1];
    f32x2 ac[4] = {};
    for (int b = beg + sub; b < end; b += 16) {
        int e1 = b + 4, e2 = b + 8, e3 = b + 12;
        uint4 u0 = *(const uint4*)&fin[(size_t)col[b] * 64 + fo];
        uint4 u1 = make_uint4(0, 0, 0, 0);
        uint4 u2 = make_uint4(0, 0, 0, 0);
        uint4 u3 = make_uint4(0, 0, 0, 0);
        if (e1 < end) u1 = *(const uint4*)&fin[(size_t)col[e1] * 64 + fo];
        if (e2 < end) u2 = *(const uint4*)&fin[(size_t)col[e2] * 64 + fo];
        if (e3 < end) u3 = *(const uint4*)&fin[(size_t)col[e3] * 64 + fo];
        ac[0] += up2v(u0.x); ac[1] += up2v(u0.y);
        ac[2] += up2v(u0.z); ac[3] += up2v(u0.w);
        ac[0] += up2v(u1.x); ac[1] += up2v(u1.y);
        ac[2] += up2v(u1.z); ac[3] += up2v(u1.w);
        ac[0] += up2v(u2.x); ac[1] += up2v(u2.y);
        ac[2] += up2v(u2.z); ac[3] += up2v(u2.w);
        ac[0] += up2v(u3.x); ac[1] += up2v(u3.y);
        ac[2] += up2v(u3.z); ac[3] += up2v(u3.w);
    }
    float a[8] = {ac[0].x, ac[0].y, ac[1].x, ac[1].y,
                  ac[2].x, ac[2].y, ac[3].x, ac[3].y};
    #pragma unroll
    for (int off = 8; off <= 16; off <<= 1)        // reduce over 4 sub-slots
        #pragma unroll
        for (int k = 0; k < 8; ++k)
            a[k] += __shfl_xor(a[k], off);
    if (sub == 0) {
        uint4 o;
        o.x = (unsigned)f2bf(a[0]) | ((unsigned)f2bf(a[1]) << 16);
        o.y = (unsigned)f2bf(a[2]) | ((unsigned)f2bf(a[3]) << 16);
        o.z = (unsigned)f2bf(a[4]) | ((unsigned)f2bf(a[5]) << 16);
        o.w = (unsigned)f2bf(a[6]) | ((unsigned)f2bf(a[7]) << 16);
        *(uint4*)&fout[(size_t)node * 64 + fo] = o;
    }
}

// ---------------- 3rd hop fused with attention combine (2 nodes/wave) ------
// MODE 0: layer 1 (res from fp32 res buffer, apply ELU); MODE 1: layer 2.
template<int MODE>
__global__ __launch_bounds__(256)
void hop3_combine_kernel(const unsigned short* __restrict__ h0,
                         const unsigned short* __restrict__ f1,
                         const unsigned short* __restrict__ f2,
                         const float* __restrict__ res, const float* __restrict__ att,
                         const float* __restrict__ bias, float* __restrict__ out,
                         const int* __restrict__ rowptr, const int* __restrict__ col, int n)
{
    int lane = threadIdx.x & 63;
    int node = blockIdx.x * 8 + ((threadIdx.x >> 6) << 1) + (lane >> 5);
    if (node >= n) return;
    int sub = (lane >> 3) & 3;      // edge slot 0..3
    int fo = (lane & 7) * 8;        // feature octet start
    size_t rbase = (size_t)node * 64 + fo;

    // f3 octet = gather-sum of f2 rows (4-deep unrolled)
    int beg = rowptr[node], end = rowptr[node + 1];
    f32x2 ac[4] = {};
    for (int b = beg + sub; b < end; b += 16) {
        int e1 = b + 4, e2 = b + 8, e3 = b + 12;
        uint4 u0 = *(const uint4*)&f2[(size_t)col[b] * 64 + fo];
        uint4 u1 = make_uint4(0, 0, 0, 0);
        uint4 u2 = make_uint4(0, 0, 0, 0);
        uint4 u3 = make_uint4(0, 0, 0, 0);
        if (e1 < end) u1 = *(const uint4*)&f2[(size_t)col[e1] * 64 + fo];
        if (e2 < end) u2 = *(const uint4*)&f2[(size_t)col[e2] * 64 + fo];
        if (e3 < end) u3 = *(const uint4*)&f2[(size_t)col[e3] * 64 + fo];
        ac[0] += up2v(u0.x); ac[1] += up2v(u0.y);
        ac[2] += up2v(u0.z); ac[3] += up2v(u0.w);
        ac[0] += up2v(u1.x); ac[1] += up2v(u1.y);
        ac[2] += up2v(u1.z); ac[3] += up2v(u1.w);
        ac[0] += up2v(u2.x); ac[1] += up2v(u2.y);
        ac[2] += up2v(u2.z); ac[3] += up2v(u2.w);
        ac[0] += up2v(u3.x); ac[1] += up2v(u3.y);
        ac[2] += up2v(u3.z); ac[3] += up2v(u3.w);
    }
    float a[8] = {ac[0].x, ac[0].y, ac[1].x, ac[1].y,
                  ac[2].x, ac[2].y, ac[3].x, ac[3].y};
    #pragma unroll
    for (int off = 8; off <= 16; off <<= 1)        // reduce over 4 sub-slots
        #pragma unroll
        for (int k = 0; k < 8; ++k)
            a[k] += __shfl_xor(a[k], off);
    // every lane of the 32-lane half now holds the full f3 octet for fo..fo+7

    uint4 r0 = *(const uint4*)&h0[rbase];
    uint4 r1 = *(const uint4*)&f1[rbase];
    uint4 r2 = *(const uint4*)&f2[rbase];
    float v0f[8] = {bflo(r0.x), bfhi(r0.x), bflo(r0.y), bfhi(r0.y),
                    bflo(r0.z), bfhi(r0.z), bflo(r0.w), bfhi(r0.w)};
    float v1f[8] = {bflo(r1.x), bfhi(r1.x), bflo(r1.y), bfhi(r1.y),
                    bflo(r1.z), bfhi(r1.z), bflo(r1.w), bfhi(r1.w)};
    float v2f[8] = {bflo(r2.x), bfhi(r2.x), bflo(r2.y), bfhi(r2.y),
                    bflo(r2.z), bfhi(r2.z), bflo(r2.w), bfhi(r2.w)};

    float4 alo0 = *(const float4*)&att[fo];
    float4 alo1 = *(const float4*)&att[fo + 4];
    float4 ahi0 = *(const float4*)&att[64 + fo];
    float4 ahi1 = *(const float4*)&att[64 + fo + 4];
    float alo[8] = {alo0.x, alo0.y, alo0.z, alo0.w, alo1.x, alo1.y, alo1.z, alo1.w};
    float ahi[8] = {ahi0.x, ahi0.y, ahi0.z, ahi0.w, ahi1.x, ahi1.y, ahi1.z, ahi1.w};

    // per-octet partial dot products, then 3-level reduce over octets
    float p0 = 0.f, q0 = 0.f, q1 = 0.f, q2 = 0.f, q3 = 0.f;
    #pragma unroll
    for (int j = 0; j < 8; ++j) {
        p0 += v0f[j] * alo[j];
        q0 += v0f[j] * ahi[j];
        q1 += v1f[j] * ahi[j];
        q2 += v2f[j] * ahi[j];
        q3 += a[j]   * ahi[j];
    }
    #pragma unroll
    for (int off = 1; off <= 4; off <<= 1) {
        p0 += __shfl_xor(p0, off);
        q0 += __shfl_xor(q0, off);
        q1 += __shfl_xor(q1, off);
        q2 += __shfl_xor(q2, off);
        q3 += __shfl_xor(q3, off);
    }

    float s0 = p0 + q0, s1 = p0 + q1, s2 = p0 + q2, s3 = p0 + q3;
    s0 = s0 > 0.f ? s0 : 0.2f * s0;
    s1 = s1 > 0.f ? s1 : 0.2f * s1;
    s2 = s2 > 0.f ? s2 : 0.2f * s2;
    s3 = s3 > 0.f ? s3 : 0.2f * s3;
    float m = fmaxf(fmaxf(s0, s1), fmaxf(s2, s3));
    float E0 = __expf(s0 - m), E1 = __expf(s1 - m);
    float E2 = __expf(s2 - m), E3 = __expf(s3 - m);
    float inv = 1.f / (E0 + E1 + E2 + E3);
    float w0 = E0 * inv, w1 = E1 * inv, w2 = E2 * inv, w3 = E3 * inv;

    float rsv[8];
    if (MODE == 0) {
        float4 ra = *(const float4*)&res[rbase];
        float4 rb = *(const float4*)&res[rbase + 4];
        rsv[0] = ra.x; rsv[1] = ra.y; rsv[2] = ra.z; rsv[3] = ra.w;
        rsv[4] = rb.x; rsv[5] = rb.y; rsv[6] = rb.z; rsv[7] = rb.w;
    } else {
        #pragma unroll
        for (int j = 0; j < 8; ++j) rsv[j] = v0f[j];
    }
    float4 ba = *(const float4*)&bias[fo];
    float4 bb = *(const float4*)&bias[fo + 4];
    float bi[8] = {ba.x, ba.y, ba.z, ba.w, bb.x, bb.y, bb.z, bb.w};

    float o[8];
    #pragma unroll
    for (int j = 0; j < 8; ++j) {
        float v = w0 * v0f[j] + w1 * v1f[j] + w2 * v2f[j] + w3 * a[j];
        v += rsv[j] + bi[j];
        if (MODE == 0) v = v > 0.f ? v : __expf(v) - 1.f;   // ELU(alpha=1)
        o[j] = v;
    }
    if (sub == 0) {
        *(float4*)&out[rbase]     = make_float4(o[0], o[1], o[2], o[3]);
        *(float4*)&out[rbase + 4] = make_float4(o[4], o[5], o[6], o[7]);
    }
}

extern "C" void kernel_launch(void* const* d_in, const int* in_sizes, int n_in,
                              void* d_out, int out_size, void* d_ws, size_t ws_size,
                              hipStream_t stream)
{
    const float* x     = (const float*)d_in[0];
    const int*   ei    = (const int*)  d_in[1];
    const float* W1    = (const float*)d_in[2];
    const float* att1  = (const float*)d_in[3];
    const float* bias1 = (const float*)d_in[4];
    const float* resW1 = (const float*)d_in[5];
    const float* W2    = (const float*)d_in[6];
    const float* att2  = (const float*)d_in[7];
    const float* bias2 = (const float*)d_in[8];

    const int N_ = in_sizes[0] / 128;
    const int E_ = in_sizes[1] / 2;
    const int* src = ei;
    const int* dst = ei + E_;

    float* out = (float*)d_out;
    size_t S = (size_t)N_ * 64;
    unsigned short* h0 = (unsigned short*)d_ws;          // S bf16
    unsigned short* f1 = h0 + S;                         // S bf16
    unsigned short* f2 = f1 + S;                         // S bf16
    int* rowptr = (int*)(f2 + S);                        // N+1
    int* col    = rowptr + (N_ + 1);                     // E

    const int NB    = (E_ + EPB - 1) / EPB;              // partition blocks (<=256)
    const int NBUCK = (N_ + 255) / 256;                  // dst buckets

    // aliases (consumed before f1 is first written by the hops)
    unsigned int* packed = (unsigned int*)f1;            // E uints
    int* table = (int*)(col + E_);                       // 256*NB
    int* exclT = table + 256 * NB;                       // 256*NB
    int* bsumT = exclT + 256 * NB;                       // 256
    unsigned short* w2b = (unsigned short*)(bsumT + 256); // 64*64 bf16

    dim3 blk(256);
    int grid_g    = (N_ + 63) / 64;
    int node_grid = (N_ + 7) / 8;
    int nT        = 256 * NB;
    int nbT       = (nT + 255) / 256;                    // == NB

    // ---------------- dispatch 1: layer-1 GEMM + coarse hist + W2 convert --
    gemm_l1_hist_kernel<<<NB + grid_g, blk, 0, stream>>>(x, W1, resW1, h0, out, N_,
                                                         dst, table, E_, NB, W2, w2b);
    // ---------------- CSR build ----------------
    scanA_kernel<<<nbT, blk, 0, stream>>>(table, exclT, bsumT, nT);
    part_scatter_kernel<<<NB, blk, 0, stream>>>(src, dst, exclT, bsumT, packed,
                                                E_, NB, nbT);
    bucket_build_kernel<<<NBUCK, blk, 0, stream>>>(packed, exclT, bsumT, rowptr, col,
                                                   E_, NB, N_, nbT);

    // ---------------- layer 1 ----------------
    hop_csr_kernel<<<node_grid, blk, 0, stream>>>(h0, f1, rowptr, col, N_);
    hop_csr_kernel<<<node_grid, blk, 0, stream>>>(f1, f2, rowptr, col, N_);
    hop3_combine_kernel<0><<<node_grid, blk, 0, stream>>>(h0, f1, f2, out, att1, bias1, out,
                                                          rowptr, col, N_);

    // ---------------- layer 2 ----------------
    gemm_l2_mfma<<<grid_g, blk, 0, stream>>>(out, w2b, h0, N_);
    hop_csr_kernel<<<node_grid, blk, 0, stream>>>(h0, f1, rowptr, col, N_);
    hop_csr_kernel<<<node_grid, blk, 0, stream>>>(f1, f2, rowptr, col, N_);
    hop3_combine_kernel<1><<<node_grid, blk, 0, stream>>>(h0, f1, f2, nullptr, att2, bias2, out,
                                                          rowptr, col, N_);
}